// Round 1
// baseline (1687.760 us; speedup 1.0000x reference)
//
#include <hip/hip_runtime.h>
#include <math.h>

// ---------------- problem constants ----------------
#define DIMD  512
#define NSEQ  4096
#define BATCH 2
#define HEADS 8
#define DHEAD 64
#define MLAND 256
#define BH    (BATCH*HEADS)      // 16
#define ROWS  (BATCH*NSEQ)       // 8192
#define QSCALE 0.125f            // 64^-0.5
#define LN_EPS 1e-5f
#define KCONV 33

// ---------------- workspace layout (float offsets) ----------------
#define OFF_XN   0ull
#define OFF_Q    4194304ull
#define OFF_K    8388608ull
#define OFF_V    12582912ull
#define OFF_Y    16777216ull
#define OFF_QL   20971520ull
#define OFF_KL   21233664ull
#define OFF_A2   21495808ull
#define OFF_ZA   22544384ull
#define OFF_ZB   23592960ull
#define OFF_TA   24641536ull
#define OFF_TB2  25690112ull
#define OFF_TB3  26738688ull
#define OFF_SIM3 27787264ull
#define OFF_A3V  44564480ull
#define OFF_WM   44826624ull
#define OFF_PART 45088768ull
#define OFF_SCAL 47185920ull
// total ~47.2M floats ~= 189 MB

// ---------------- helpers ----------------
__device__ __forceinline__ float block_red(float v, float* s4, bool sum) {
  // 256-thread block: wave butterfly then cross-wave via LDS
#pragma unroll
  for (int o = 32; o; o >>= 1) {
    float t = __shfl_xor(v, o);
    v = sum ? v + t : fmaxf(v, t);
  }
  int wid = threadIdx.x >> 6;
  if ((threadIdx.x & 63) == 0) s4[wid] = v;
  __syncthreads();
  float r = sum ? (s4[0] + s4[1] + s4[2] + s4[3])
                : fmaxf(fmaxf(s4[0], s4[1]), fmaxf(s4[2], s4[3]));
  __syncthreads();
  return r;
}

#define FMA16() do { \
  float4 a_ = *(const float4*)&As[kk][tm*4]; \
  float4 b_ = *(const float4*)&Bs[kk][tn*4]; \
  acc[0][0]+=a_.x*b_.x; acc[0][1]+=a_.x*b_.y; acc[0][2]+=a_.x*b_.z; acc[0][3]+=a_.x*b_.w; \
  acc[1][0]+=a_.y*b_.x; acc[1][1]+=a_.y*b_.y; acc[1][2]+=a_.y*b_.z; acc[1][3]+=a_.y*b_.w; \
  acc[2][0]+=a_.z*b_.x; acc[2][1]+=a_.z*b_.y; acc[2][2]+=a_.z*b_.z; acc[2][3]+=a_.z*b_.w; \
  acc[3][0]+=a_.w*b_.x; acc[3][1]+=a_.w*b_.y; acc[3][2]+=a_.w*b_.z; acc[3][3]+=a_.w*b_.w; \
} while (0)

// ---------------- kernels ----------------

__global__ void k_init(unsigned* scal) {
  if (threadIdx.x < 2) scal[threadIdx.x] = 0u;
}

// LayerNorm: one wave per row of 512
__global__ __launch_bounds__(256) void k_ln(const float* __restrict__ x,
                                            const float* __restrict__ w,
                                            const float* __restrict__ b,
                                            float* __restrict__ xn) {
  int lane = threadIdx.x & 63;
  int row = blockIdx.x * 4 + (threadIdx.x >> 6);
  const float* xr = x + (size_t)row * DIMD;
  float4 v0 = *(const float4*)&xr[lane * 8];
  float4 v1 = *(const float4*)&xr[lane * 8 + 4];
  float s  = v0.x + v0.y + v0.z + v0.w + v1.x + v1.y + v1.z + v1.w;
  float ss = v0.x*v0.x + v0.y*v0.y + v0.z*v0.z + v0.w*v0.w
           + v1.x*v1.x + v1.y*v1.y + v1.z*v1.z + v1.w*v1.w;
#pragma unroll
  for (int o = 32; o; o >>= 1) { s += __shfl_xor(s, o); ss += __shfl_xor(ss, o); }
  float mu = s * (1.f / 512.f);
  float var = ss * (1.f / 512.f) - mu * mu;
  float rstd = rsqrtf(var + LN_EPS);
  float4 w0 = *(const float4*)&w[lane * 8];
  float4 w1 = *(const float4*)&w[lane * 8 + 4];
  float4 b0 = *(const float4*)&b[lane * 8];
  float4 b1 = *(const float4*)&b[lane * 8 + 4];
  float4 o0, o1;
  o0.x = (v0.x - mu) * rstd * w0.x + b0.x;
  o0.y = (v0.y - mu) * rstd * w0.y + b0.y;
  o0.z = (v0.z - mu) * rstd * w0.z + b0.z;
  o0.w = (v0.w - mu) * rstd * w0.w + b0.w;
  o1.x = (v1.x - mu) * rstd * w1.x + b1.x;
  o1.y = (v1.y - mu) * rstd * w1.y + b1.y;
  o1.z = (v1.z - mu) * rstd * w1.z + b1.z;
  o1.w = (v1.w - mu) * rstd * w1.w + b1.w;
  *(float4*)&xn[(size_t)row * DIMD + lane * 8] = o0;
  *(float4*)&xn[(size_t)row * DIMD + lane * 8 + 4] = o1;
}

// QKV projection: C[m,c] = sum_k xn[m,k]*qkv_w[c,k]; scatter into [BH][N][64] q/k/v
__global__ __launch_bounds__(256) void k_qkv(const float* __restrict__ A,
                                             const float* __restrict__ W,
                                             float* __restrict__ qb,
                                             float* __restrict__ kb,
                                             float* __restrict__ vb) {
  __shared__ float As[16][68], Bs[16][68];
  const int tid = threadIdx.x;
  const int m0 = blockIdx.y * 64, c0 = blockIdx.x * 64;
  const int tm = tid >> 4, tn = tid & 15;
  const int lr = tid >> 2, lk = (tid & 3) * 4;
  float acc[4][4] = {};
  for (int k0 = 0; k0 < 512; k0 += 16) {
    float4 av = *(const float4*)&A[(size_t)(m0 + lr) * 512 + k0 + lk];
    float4 bv = *(const float4*)&W[(size_t)(c0 + lr) * 512 + k0 + lk];
    As[lk + 0][lr] = av.x; As[lk + 1][lr] = av.y; As[lk + 2][lr] = av.z; As[lk + 3][lr] = av.w;
    Bs[lk + 0][lr] = bv.x; Bs[lk + 1][lr] = bv.y; Bs[lk + 2][lr] = bv.z; Bs[lk + 3][lr] = bv.w;
    __syncthreads();
#pragma unroll
    for (int kk = 0; kk < 16; ++kk) FMA16();
    __syncthreads();
  }
  const int which = c0 >> 9, h = (c0 >> 6) & 7;
  float* dst = which == 0 ? qb : (which == 1 ? kb : vb);
  const float sc = which == 0 ? QSCALE : 1.f;
#pragma unroll
  for (int i = 0; i < 4; ++i) {
    int m = m0 + tm * 4 + i;
    int bb = m >> 12, n = m & 4095;
    float4 st;
    st.x = acc[i][0] * sc; st.y = acc[i][1] * sc;
    st.z = acc[i][2] * sc; st.w = acc[i][3] * sc;
    *(float4*)&dst[(size_t)((bb * 8 + h) * 4096 + n) * 64 + tn * 4] = st;
  }
}

// landmark means (l=16)
__global__ __launch_bounds__(256) void k_land(const float* __restrict__ q,
                                              const float* __restrict__ k,
                                              float* __restrict__ ql,
                                              float* __restrict__ kl) {
  int idx = blockIdx.x * 256 + threadIdx.x;
  int sel = idx >= (BH * MLAND * DHEAD);
  int e = sel ? idx - BH * MLAND * DHEAD : idx;
  int bh = e >> 14; int m = (e >> 6) & 255; int d = e & 63;
  const float* src = sel ? k : q;
  size_t base = ((size_t)bh * 4096 + m * 16) * 64 + d;
  float s = 0;
#pragma unroll
  for (int t = 0; t < 16; ++t) s += src[base + t * 64];
  (sel ? kl : ql)[e] = s * (1.f / 16.f);
}

// sim2 + row softmax -> a2 [BH][256][256]
__global__ __launch_bounds__(256) void k_sim2(const float* __restrict__ ql,
                                              const float* __restrict__ kl,
                                              float* __restrict__ a2) {
  __shared__ float qs[64];
  __shared__ float s4[4];
  int i = blockIdx.x, bh = blockIdx.y, tid = threadIdx.x;
  if (tid < 16) ((float4*)qs)[tid] = ((const float4*)(ql + ((size_t)bh * 256 + i) * 64))[tid];
  __syncthreads();
  const float* kr = kl + ((size_t)bh * 256 + tid) * 64;
  float s = 0;
#pragma unroll
  for (int d = 0; d < 64; d += 4) {
    float4 kv = *(const float4*)&kr[d];
    s += qs[d] * kv.x + qs[d + 1] * kv.y + qs[d + 2] * kv.z + qs[d + 3] * kv.w;
  }
  float mx = block_red(s, s4, false);
  float p = expf(s - mx);
  float tot = block_red(p, s4, true);
  a2[((size_t)bh * 256 + i) * 256 + tid] = p / tot;
}

// global max of |row-sum| and |col-sum| over all bh
__global__ __launch_bounds__(256) void k_pinv_red(const float* __restrict__ a2,
                                                  unsigned* __restrict__ scal) {
  __shared__ float s4[4];
  int bh = blockIdx.x, tid = threadIdx.x;
  const float* m = a2 + (size_t)bh * 65536;
  float cs = 0;
  for (int i = 0; i < 256; ++i) cs += fabsf(m[(size_t)i * 256 + tid]);
  float rs = 0;
  const float* row = m + (size_t)tid * 256;
  for (int j = 0; j < 256; j += 4) {
    float4 v = *(const float4*)&row[j];
    rs += fabsf(v.x) + fabsf(v.y) + fabsf(v.z) + fabsf(v.w);
  }
  float mc = block_red(cs, s4, false);
  float mr = block_red(rs, s4, false);
  if (tid == 0) {
    atomicMax(&scal[0], __float_as_uint(mr));
    atomicMax(&scal[1], __float_as_uint(mc));
  }
}

// z0 = a2^T / (R*C)
__global__ __launch_bounds__(256) void k_z0(const float* __restrict__ a2,
                                            const unsigned* __restrict__ scal,
                                            float* __restrict__ z) {
  int idx = blockIdx.x * 256 + threadIdx.x;
  float inv = 1.f / (__uint_as_float(scal[0]) * __uint_as_float(scal[1]));
  int bh = idx >> 16, r = (idx >> 8) & 255, c = idx & 255;
  z[idx] = a2[((size_t)bh << 16) + (c << 8) + r] * inv;
}

// batched 256^3 GEMM: C = aI*I + s * P @ (g*Q + bI*I)
__global__ __launch_bounds__(256) void k_pg(const float* __restrict__ P,
                                            const float* __restrict__ Q,
                                            float* __restrict__ C,
                                            float aI, float s, float g, float bI) {
  __shared__ float As[16][68], Bs[16][68];
  int tid = threadIdx.x;
  int bh = blockIdx.z;
  int i0 = blockIdx.y * 64, j0 = blockIdx.x * 64;
  P += (size_t)bh * 65536; Q += (size_t)bh * 65536; C += (size_t)bh * 65536;
  int tm = tid >> 4, tn = tid & 15, lr = tid >> 2, lk = (tid & 3) * 4;
  int qk = tid >> 4, qj = (tid & 15) * 4;
  float acc[4][4] = {};
  for (int k0 = 0; k0 < 256; k0 += 16) {
    float4 pv = *(const float4*)&P[(size_t)(i0 + lr) * 256 + k0 + lk];
    As[lk + 0][lr] = pv.x; As[lk + 1][lr] = pv.y; As[lk + 2][lr] = pv.z; As[lk + 3][lr] = pv.w;
    float4 qv = *(const float4*)&Q[(size_t)(k0 + qk) * 256 + j0 + qj];
    int krow = k0 + qk, jc = j0 + qj;
    Bs[qk][qj + 0] = g * qv.x + (krow == jc + 0 ? bI : 0.f);
    Bs[qk][qj + 1] = g * qv.y + (krow == jc + 1 ? bI : 0.f);
    Bs[qk][qj + 2] = g * qv.z + (krow == jc + 2 ? bI : 0.f);
    Bs[qk][qj + 3] = g * qv.w + (krow == jc + 3 ? bI : 0.f);
    __syncthreads();
#pragma unroll
    for (int kk = 0; kk < 16; ++kk) FMA16();
    __syncthreads();
  }
#pragma unroll
  for (int i = 0; i < 4; ++i) {
    int ii = i0 + tm * 4 + i;
    int jj = j0 + tn * 4;
    float4 st;
    st.x = (ii == jj + 0 ? aI : 0.f) + s * acc[i][0];
    st.y = (ii == jj + 1 ? aI : 0.f) + s * acc[i][1];
    st.z = (ii == jj + 2 ? aI : 0.f) + s * acc[i][2];
    st.w = (ii == jj + 3 ? aI : 0.f) + s * acc[i][3];
    *(float4*)&C[(size_t)ii * 256 + jj] = st;
  }
}

// sim3[bh][m][n] = q_land[m] . k[n]  (NT, K=64)
__global__ __launch_bounds__(256) void k_sim3(const float* __restrict__ ql,
                                              const float* __restrict__ kmat,
                                              float* __restrict__ sim3) {
  __shared__ float As[16][68], Bs[16][68];
  int tid = threadIdx.x, bh = blockIdx.z;
  int m0 = blockIdx.y * 64, n0 = blockIdx.x * 64;
  const float* A = ql + (size_t)bh * 256 * 64;
  const float* B = kmat + (size_t)bh * 4096 * 64;
  float* Cm = sim3 + (size_t)bh * 256 * 4096;
  int tm = tid >> 4, tn = tid & 15, lr = tid >> 2, lk = (tid & 3) * 4;
  float acc[4][4] = {};
  for (int k0 = 0; k0 < 64; k0 += 16) {
    float4 av = *(const float4*)&A[(size_t)(m0 + lr) * 64 + k0 + lk];
    float4 bv = *(const float4*)&B[(size_t)(n0 + lr) * 64 + k0 + lk];
    As[lk + 0][lr] = av.x; As[lk + 1][lr] = av.y; As[lk + 2][lr] = av.z; As[lk + 3][lr] = av.w;
    Bs[lk + 0][lr] = bv.x; Bs[lk + 1][lr] = bv.y; Bs[lk + 2][lr] = bv.z; Bs[lk + 3][lr] = bv.w;
    __syncthreads();
#pragma unroll
    for (int kk = 0; kk < 16; ++kk) FMA16();
    __syncthreads();
  }
#pragma unroll
  for (int i = 0; i < 4; ++i) {
    float4 st; st.x = acc[i][0]; st.y = acc[i][1]; st.z = acc[i][2]; st.w = acc[i][3];
    *(float4*)&Cm[(size_t)(m0 + tm * 4 + i) * 4096 + n0 + tn * 4] = st;
  }
}

// in-place row softmax over 4096
__global__ __launch_bounds__(256) void k_sm4096(float* __restrict__ sim) {
  __shared__ float s4[4];
  int m = blockIdx.x, bh = blockIdx.y, tid = threadIdx.x;
  float* row = sim + ((size_t)bh * 256 + m) * 4096;
  float v[16];
  float mx = -1e30f;
#pragma unroll
  for (int i = 0; i < 16; ++i) { v[i] = row[i * 256 + tid]; mx = fmaxf(mx, v[i]); }
  mx = block_red(mx, s4, false);
  float ssum = 0;
#pragma unroll
  for (int i = 0; i < 16; ++i) { v[i] = expf(v[i] - mx); ssum += v[i]; }
  ssum = block_red(ssum, s4, true);
  float inv = 1.f / ssum;
#pragma unroll
  for (int i = 0; i < 16; ++i) row[i * 256 + tid] = v[i] * inv;
}

// a3 @ v  split-K partials  (A [256,4096] row-major, B=v [4096,64])
__global__ __launch_bounds__(256) void k_a3v(const float* __restrict__ a3,
                                             const float* __restrict__ v,
                                             float* __restrict__ part) {
  __shared__ float As[16][68], Bs[16][68];
  int tid = threadIdx.x;
  int kc = blockIdx.x, m0 = blockIdx.y * 64, bh = blockIdx.z;
  const float* A = a3 + (size_t)bh * 256 * 4096;
  const float* B = v + (size_t)bh * 4096 * 64;
  int tm = tid >> 4, tn = tid & 15, lr = tid >> 2, lk = (tid & 3) * 4;
  int qk = tid >> 4, qj = (tid & 15) * 4;
  float acc[4][4] = {};
  int kbeg = kc * 512;
  for (int k0 = kbeg; k0 < kbeg + 512; k0 += 16) {
    float4 av = *(const float4*)&A[(size_t)(m0 + lr) * 4096 + k0 + lk];
    As[lk + 0][lr] = av.x; As[lk + 1][lr] = av.y; As[lk + 2][lr] = av.z; As[lk + 3][lr] = av.w;
    float4 bv = *(const float4*)&B[(size_t)(k0 + qk) * 64 + qj];
    Bs[qk][qj + 0] = bv.x; Bs[qk][qj + 1] = bv.y; Bs[qk][qj + 2] = bv.z; Bs[qk][qj + 3] = bv.w;
    __syncthreads();
#pragma unroll
    for (int kk = 0; kk < 16; ++kk) FMA16();
    __syncthreads();
  }
#pragma unroll
  for (int i = 0; i < 4; ++i) {
    float4 st; st.x = acc[i][0]; st.y = acc[i][1]; st.z = acc[i][2]; st.w = acc[i][3];
    *(float4*)&part[(((size_t)kc * 16 + bh) * 256 + m0 + tm * 4 + i) * 64 + tn * 4] = st;
  }
}

__global__ __launch_bounds__(256) void k_a3v_red(const float* __restrict__ part,
                                                 float* __restrict__ a3v) {
  int idx = blockIdx.x * 256 + threadIdx.x;
  float s = 0;
#pragma unroll
  for (int c = 0; c < 8; ++c) s += part[(size_t)c * 262144 + idx];
  a3v[idx] = s;
}

// wm = z @ a3v  ([256,256]@[256,64])
__global__ __launch_bounds__(256) void k_wm(const float* __restrict__ z,
                                            const float* __restrict__ a3v,
                                            float* __restrict__ wm) {
  __shared__ float As[16][68], Bs[16][68];
  int tid = threadIdx.x;
  int m0 = blockIdx.y * 64, bh = blockIdx.z;
  const float* P = z + (size_t)bh * 65536;
  const float* Q = a3v + (size_t)bh * 16384;
  int tm = tid >> 4, tn = tid & 15, lr = tid >> 2, lk = (tid & 3) * 4;
  int qk = tid >> 4, qj = (tid & 15) * 4;
  float acc[4][4] = {};
  for (int k0 = 0; k0 < 256; k0 += 16) {
    float4 pv = *(const float4*)&P[(size_t)(m0 + lr) * 256 + k0 + lk];
    As[lk + 0][lr] = pv.x; As[lk + 1][lr] = pv.y; As[lk + 2][lr] = pv.z; As[lk + 3][lr] = pv.w;
    float4 qv = *(const float4*)&Q[(size_t)(k0 + qk) * 64 + qj];
    Bs[qk][qj + 0] = qv.x; Bs[qk][qj + 1] = qv.y; Bs[qk][qj + 2] = qv.z; Bs[qk][qj + 3] = qv.w;
    __syncthreads();
#pragma unroll
    for (int kk = 0; kk < 16; ++kk) FMA16();
    __syncthreads();
  }
#pragma unroll
  for (int i = 0; i < 4; ++i) {
    float4 st; st.x = acc[i][0]; st.y = acc[i][1]; st.z = acc[i][2]; st.w = acc[i][3];
    *(float4*)&wm[((size_t)bh * 256 + m0 + tm * 4 + i) * 64 + tn * 4] = st;
  }
}

// per (b,h,n): sim1 row -> softmax -> @wm, plus depthwise conv residual; write y[b][n][h*64+d]
__global__ __launch_bounds__(256) void k_fused(const float* __restrict__ q,
                                               const float* __restrict__ kl,
                                               const float* __restrict__ wm,
                                               const float* __restrict__ v,
                                               const float* __restrict__ cw,
                                               float* __restrict__ y) {
  __shared__ float qs[64];
  __shared__ float ps[256];
  __shared__ float op[4][64];
  __shared__ float s4[4];
  int n = blockIdx.x, h = blockIdx.y, b = blockIdx.z;
  int bh = b * HEADS + h, tid = threadIdx.x;
  if (tid < 16) ((float4*)qs)[tid] = ((const float4*)(q + ((size_t)bh * 4096 + n) * 64))[tid];
  __syncthreads();
  const float* kr = kl + ((size_t)bh * 256 + tid) * 64;
  float s = 0;
#pragma unroll
  for (int d = 0; d < 64; d += 4) {
    float4 kv = *(const float4*)&kr[d];
    s += qs[d] * kv.x + qs[d + 1] * kv.y + qs[d + 2] * kv.z + qs[d + 3] * kv.w;
  }
  float mx = block_red(s, s4, false);
  float p = expf(s - mx);
  ps[tid] = p;
  float tot = block_red(p, s4, true);
  float inv = 1.f / tot;
  int d = tid & 63, part = tid >> 6;
  const float* wr = wm + (size_t)bh * 256 * 64;
  float o = 0;
  for (int j = part * 64; j < part * 64 + 64; ++j) o += ps[j] * wr[(size_t)j * 64 + d];
  op[part][d] = o;
  __syncthreads();
  if (tid < 64) {
    float oo = (op[0][d] + op[1][d] + op[2][d] + op[3][d]) * inv;
    float res = 0;
    const float* vb = v + (size_t)bh * 4096 * 64;
#pragma unroll
    for (int t = 0; t < KCONV; ++t) {
      int nn = n - 16 + t;
      if (nn >= 0 && nn < 4096) res += cw[h * KCONV + t] * vb[(size_t)nn * 64 + d];
    }
    y[((size_t)b * 4096 + n) * 512 + h * 64 + d] = oo + res;
  }
}

// out = x + y @ out_w^T + out_b
__global__ __launch_bounds__(256) void k_outproj(const float* __restrict__ Y,
                                                 const float* __restrict__ W,
                                                 const float* __restrict__ bias,
                                                 const float* __restrict__ x,
                                                 float* __restrict__ out) {
  __shared__ float As[16][68], Bs[16][68];
  int tid = threadIdx.x;
  int m0 = blockIdx.y * 64, c0 = blockIdx.x * 64;
  int tm = tid >> 4, tn = tid & 15, lr = tid >> 2, lk = (tid & 3) * 4;
  float acc[4][4] = {};
  for (int k0 = 0; k0 < 512; k0 += 16) {
    float4 av = *(const float4*)&Y[(size_t)(m0 + lr) * 512 + k0 + lk];
    float4 bv = *(const float4*)&W[(size_t)(c0 + lr) * 512 + k0 + lk];
    As[lk + 0][lr] = av.x; As[lk + 1][lr] = av.y; As[lk + 2][lr] = av.z; As[lk + 3][lr] = av.w;
    Bs[lk + 0][lr] = bv.x; Bs[lk + 1][lr] = bv.y; Bs[lk + 2][lr] = bv.z; Bs[lk + 3][lr] = bv.w;
    __syncthreads();
#pragma unroll
    for (int kk = 0; kk < 16; ++kk) FMA16();
    __syncthreads();
  }
  float4 bb = *(const float4*)&bias[c0 + tn * 4];
#pragma unroll
  for (int i = 0; i < 4; ++i) {
    int m = m0 + tm * 4 + i;
    float4 xv = *(const float4*)&x[(size_t)m * 512 + c0 + tn * 4];
    float4 st;
    st.x = acc[i][0] + xv.x + bb.x;
    st.y = acc[i][1] + xv.y + bb.y;
    st.z = acc[i][2] + xv.z + bb.z;
    st.w = acc[i][3] + xv.w + bb.w;
    *(float4*)&out[(size_t)m * 512 + c0 + tn * 4] = st;
  }
}

// ---------------- launcher ----------------
extern "C" void kernel_launch(void* const* d_in, const int* in_sizes, int n_in,
                              void* d_out, int out_size, void* d_ws, size_t ws_size,
                              hipStream_t stream) {
  const float* x      = (const float*)d_in[0];
  const float* ln_w   = (const float*)d_in[1];
  const float* ln_b   = (const float*)d_in[2];
  const float* qkv_w  = (const float*)d_in[3];
  const float* out_w  = (const float*)d_in[4];
  const float* out_b  = (const float*)d_in[5];
  const float* conv_w = (const float*)d_in[6];
  float* wsf = (float*)d_ws;
  float* out = (float*)d_out;

  float* xn   = wsf + OFF_XN;
  float* q    = wsf + OFF_Q;
  float* k    = wsf + OFF_K;
  float* v    = wsf + OFF_V;
  float* y    = wsf + OFF_Y;
  float* ql   = wsf + OFF_QL;
  float* kl   = wsf + OFF_KL;
  float* a2   = wsf + OFF_A2;
  float* zA   = wsf + OFF_ZA;
  float* zB   = wsf + OFF_ZB;
  float* tA   = wsf + OFF_TA;
  float* tB2  = wsf + OFF_TB2;
  float* tB3  = wsf + OFF_TB3;
  float* sim3 = wsf + OFF_SIM3;
  float* a3v  = wsf + OFF_A3V;
  float* wm   = wsf + OFF_WM;
  float* part = wsf + OFF_PART;
  unsigned* scal = (unsigned*)(wsf + OFF_SCAL);

  k_init<<<1, 64, 0, stream>>>(scal);
  k_ln<<<2048, 256, 0, stream>>>(x, ln_w, ln_b, xn);
  k_qkv<<<dim3(24, 128), 256, 0, stream>>>(xn, qkv_w, q, k, v);
  k_land<<<2048, 256, 0, stream>>>(q, k, ql, kl);
  k_sim2<<<dim3(256, 16), 256, 0, stream>>>(ql, kl, a2);
  k_pinv_red<<<16, 256, 0, stream>>>(a2, scal);
  k_z0<<<4096, 256, 0, stream>>>(a2, scal, zA);

  dim3 g44(4, 4, 16);
  float* zc = zA; float* zn = zB;
  for (int it = 0; it < 6; ++it) {
    k_pg<<<g44, 256, 0, stream>>>(a2, zc, tA, 0.f, 1.f, 1.f, 0.f);     // A  = a2 @ z
    k_pg<<<g44, 256, 0, stream>>>(tA, tA, tB2, 15.f, -1.f, -1.f, 7.f); // B2 = 15I - A@(7I-A)
    k_pg<<<g44, 256, 0, stream>>>(tA, tB2, tB3, 13.f, -1.f, 1.f, 0.f); // B3 = 13I - A@B2
    k_pg<<<g44, 256, 0, stream>>>(zc, tB3, zn, 0.f, 0.25f, 1.f, 0.f);  // z  = 0.25 z@B3
    float* t = zc; zc = zn; zn = t;
  }

  k_sim3<<<dim3(64, 4, 16), 256, 0, stream>>>(ql, k, sim3);
  k_sm4096<<<dim3(256, 16), 256, 0, stream>>>(sim3);
  k_a3v<<<dim3(8, 4, 16), 256, 0, stream>>>(sim3, v, part);
  k_a3v_red<<<1024, 256, 0, stream>>>(part, a3v);
  k_wm<<<dim3(1, 4, 16), 256, 0, stream>>>(zc, a3v, wm);
  k_fused<<<dim3(4096, 8, 2), 256, 0, stream>>>(q, kl, wm, v, conv_w, y);
  k_outproj<<<dim3(8, 128), 256, 0, stream>>>(y, out_w, out_b, x, out);
}

// Round 2
// 966.827 us; speedup vs baseline: 1.7457x; 1.7457x over previous
//
#include <hip/hip_runtime.h>
#include <math.h>

// ---------------- problem constants ----------------
#define DIMD  512
#define NSEQ  4096
#define BATCH 2
#define HEADS 8
#define DHEAD 64
#define MLAND 256
#define BH    (BATCH*HEADS)      // 16
#define ROWS  (BATCH*NSEQ)       // 8192
#define QSCALE 0.125f            // 64^-0.5
#define LN_EPS 1e-5f
#define KCONV 33

// ---------------- workspace layout (float offsets) ----------------
#define OFF_XN   0ull
#define OFF_Q    4194304ull
#define OFF_K    8388608ull
#define OFF_V    12582912ull
#define OFF_Y    16777216ull
#define OFF_QL   20971520ull
#define OFF_KL   21233664ull
#define OFF_A2   21495808ull
#define OFF_ZA   22544384ull
#define OFF_ZB   23592960ull
#define OFF_TA   24641536ull
#define OFF_TB2  25690112ull
#define OFF_TB3  26738688ull
#define OFF_SIM3 27787264ull
#define OFF_A3V  44564480ull
#define OFF_WM   44826624ull
#define OFF_PART 45088768ull
#define OFF_SCAL 47185920ull
// total ~47.2M floats ~= 189 MB

// ---------------- helpers ----------------
__device__ __forceinline__ float block_red(float v, float* s4, bool sum) {
#pragma unroll
  for (int o = 32; o; o >>= 1) {
    float t = __shfl_xor(v, o);
    v = sum ? v + t : fmaxf(v, t);
  }
  int wid = threadIdx.x >> 6;
  if ((threadIdx.x & 63) == 0) s4[wid] = v;
  __syncthreads();
  float r = sum ? (s4[0] + s4[1] + s4[2] + s4[3])
                : fmaxf(fmaxf(s4[0], s4[1]), fmaxf(s4[2], s4[3]));
  __syncthreads();
  return r;
}

#define FMA16() do { \
  float4 a_ = *(const float4*)&As[kk][tm*4]; \
  float4 b_ = *(const float4*)&Bs[kk][tn*4]; \
  acc[0][0]+=a_.x*b_.x; acc[0][1]+=a_.x*b_.y; acc[0][2]+=a_.x*b_.z; acc[0][3]+=a_.x*b_.w; \
  acc[1][0]+=a_.y*b_.x; acc[1][1]+=a_.y*b_.y; acc[1][2]+=a_.y*b_.z; acc[1][3]+=a_.y*b_.w; \
  acc[2][0]+=a_.z*b_.x; acc[2][1]+=a_.z*b_.y; acc[2][2]+=a_.z*b_.z; acc[2][3]+=a_.z*b_.w; \
  acc[3][0]+=a_.w*b_.x; acc[3][1]+=a_.w*b_.y; acc[3][2]+=a_.w*b_.z; acc[3][3]+=a_.w*b_.w; \
} while (0)

// ---------------- kernels ----------------

__global__ void k_init(unsigned* scal) {
  if (threadIdx.x < 2) scal[threadIdx.x] = 0u;
}

// LayerNorm: one wave per row of 512
__global__ __launch_bounds__(256) void k_ln(const float* __restrict__ x,
                                            const float* __restrict__ w,
                                            const float* __restrict__ b,
                                            float* __restrict__ xn) {
  int lane = threadIdx.x & 63;
  int row = blockIdx.x * 4 + (threadIdx.x >> 6);
  const float* xr = x + (size_t)row * DIMD;
  float4 v0 = *(const float4*)&xr[lane * 8];
  float4 v1 = *(const float4*)&xr[lane * 8 + 4];
  float s  = v0.x + v0.y + v0.z + v0.w + v1.x + v1.y + v1.z + v1.w;
  float ss = v0.x*v0.x + v0.y*v0.y + v0.z*v0.z + v0.w*v0.w
           + v1.x*v1.x + v1.y*v1.y + v1.z*v1.z + v1.w*v1.w;
#pragma unroll
  for (int o = 32; o; o >>= 1) { s += __shfl_xor(s, o); ss += __shfl_xor(ss, o); }
  float mu = s * (1.f / 512.f);
  float var = ss * (1.f / 512.f) - mu * mu;
  float rstd = rsqrtf(var + LN_EPS);
  float4 w0 = *(const float4*)&w[lane * 8];
  float4 w1 = *(const float4*)&w[lane * 8 + 4];
  float4 b0 = *(const float4*)&b[lane * 8];
  float4 b1 = *(const float4*)&b[lane * 8 + 4];
  float4 o0, o1;
  o0.x = (v0.x - mu) * rstd * w0.x + b0.x;
  o0.y = (v0.y - mu) * rstd * w0.y + b0.y;
  o0.z = (v0.z - mu) * rstd * w0.z + b0.z;
  o0.w = (v0.w - mu) * rstd * w0.w + b0.w;
  o1.x = (v1.x - mu) * rstd * w1.x + b1.x;
  o1.y = (v1.y - mu) * rstd * w1.y + b1.y;
  o1.z = (v1.z - mu) * rstd * w1.z + b1.z;
  o1.w = (v1.w - mu) * rstd * w1.w + b1.w;
  *(float4*)&xn[(size_t)row * DIMD + lane * 8] = o0;
  *(float4*)&xn[(size_t)row * DIMD + lane * 8 + 4] = o1;
}

// QKV projection: C[m,c] = sum_k xn[m,k]*qkv_w[c,k]; scatter into [BH][N][64] q/k/v
__global__ __launch_bounds__(256) void k_qkv(const float* __restrict__ A,
                                             const float* __restrict__ W,
                                             float* __restrict__ qb,
                                             float* __restrict__ kb,
                                             float* __restrict__ vb) {
  __shared__ float As[16][68], Bs[16][68];
  const int tid = threadIdx.x;
  const int m0 = blockIdx.y * 64, c0 = blockIdx.x * 64;
  const int tm = tid >> 4, tn = tid & 15;
  const int lr = tid >> 2, lk = (tid & 3) * 4;
  float acc[4][4] = {};
  for (int k0 = 0; k0 < 512; k0 += 16) {
    float4 av = *(const float4*)&A[(size_t)(m0 + lr) * 512 + k0 + lk];
    float4 bv = *(const float4*)&W[(size_t)(c0 + lr) * 512 + k0 + lk];
    As[lk + 0][lr] = av.x; As[lk + 1][lr] = av.y; As[lk + 2][lr] = av.z; As[lk + 3][lr] = av.w;
    Bs[lk + 0][lr] = bv.x; Bs[lk + 1][lr] = bv.y; Bs[lk + 2][lr] = bv.z; Bs[lk + 3][lr] = bv.w;
    __syncthreads();
#pragma unroll
    for (int kk = 0; kk < 16; ++kk) FMA16();
    __syncthreads();
  }
  const int which = c0 >> 9, h = (c0 >> 6) & 7;
  float* dst = which == 0 ? qb : (which == 1 ? kb : vb);
  const float sc = which == 0 ? QSCALE : 1.f;
#pragma unroll
  for (int i = 0; i < 4; ++i) {
    int m = m0 + tm * 4 + i;
    int bb = m >> 12, n = m & 4095;
    float4 st;
    st.x = acc[i][0] * sc; st.y = acc[i][1] * sc;
    st.z = acc[i][2] * sc; st.w = acc[i][3] * sc;
    *(float4*)&dst[(size_t)((bb * 8 + h) * 4096 + n) * 64 + tn * 4] = st;
  }
}

// landmark means (l=16)
__global__ __launch_bounds__(256) void k_land(const float* __restrict__ q,
                                              const float* __restrict__ k,
                                              float* __restrict__ ql,
                                              float* __restrict__ kl) {
  int idx = blockIdx.x * 256 + threadIdx.x;
  int sel = idx >= (BH * MLAND * DHEAD);
  int e = sel ? idx - BH * MLAND * DHEAD : idx;
  int bh = e >> 14; int m = (e >> 6) & 255; int d = e & 63;
  const float* src = sel ? k : q;
  size_t base = ((size_t)bh * 4096 + m * 16) * 64 + d;
  float s = 0;
#pragma unroll
  for (int t = 0; t < 16; ++t) s += src[base + t * 64];
  (sel ? kl : ql)[e] = s * (1.f / 16.f);
}

// sim2 + row softmax -> a2 [BH][256][256]
__global__ __launch_bounds__(256) void k_sim2(const float* __restrict__ ql,
                                              const float* __restrict__ kl,
                                              float* __restrict__ a2) {
  __shared__ float qs[64];
  __shared__ float s4[4];
  int i = blockIdx.x, bh = blockIdx.y, tid = threadIdx.x;
  if (tid < 16) ((float4*)qs)[tid] = ((const float4*)(ql + ((size_t)bh * 256 + i) * 64))[tid];
  __syncthreads();
  const float* kr = kl + ((size_t)bh * 256 + tid) * 64;
  float s = 0;
#pragma unroll
  for (int d = 0; d < 64; d += 4) {
    float4 kv = *(const float4*)&kr[d];
    s += qs[d] * kv.x + qs[d + 1] * kv.y + qs[d + 2] * kv.z + qs[d + 3] * kv.w;
  }
  float mx = block_red(s, s4, false);
  float p = expf(s - mx);
  float tot = block_red(p, s4, true);
  a2[((size_t)bh * 256 + i) * 256 + tid] = p / tot;
}

// global max of |row-sum| and |col-sum| over all bh
__global__ __launch_bounds__(256) void k_pinv_red(const float* __restrict__ a2,
                                                  unsigned* __restrict__ scal) {
  __shared__ float s4[4];
  int bh = blockIdx.x, tid = threadIdx.x;
  const float* m = a2 + (size_t)bh * 65536;
  float cs = 0;
  for (int i = 0; i < 256; ++i) cs += fabsf(m[(size_t)i * 256 + tid]);
  float rs = 0;
  const float* row = m + (size_t)tid * 256;
  for (int j = 0; j < 256; j += 4) {
    float4 v = *(const float4*)&row[j];
    rs += fabsf(v.x) + fabsf(v.y) + fabsf(v.z) + fabsf(v.w);
  }
  float mc = block_red(cs, s4, false);
  float mr = block_red(rs, s4, false);
  if (tid == 0) {
    atomicMax(&scal[0], __float_as_uint(mr));
    atomicMax(&scal[1], __float_as_uint(mc));
  }
}

// z0 = a2^T / (R*C)
__global__ __launch_bounds__(256) void k_z0(const float* __restrict__ a2,
                                            const unsigned* __restrict__ scal,
                                            float* __restrict__ z) {
  int idx = blockIdx.x * 256 + threadIdx.x;
  float inv = 1.f / (__uint_as_float(scal[0]) * __uint_as_float(scal[1]));
  int bh = idx >> 16, r = (idx >> 8) & 255, c = idx & 255;
  z[idx] = a2[((size_t)bh << 16) + (c << 8) + r] * inv;
}

// batched 256^3 GEMM: C = aI*I + s * P @ (g*Q + bI*I)
__global__ __launch_bounds__(256) void k_pg(const float* __restrict__ P,
                                            const float* __restrict__ Q,
                                            float* __restrict__ C,
                                            float aI, float s, float g, float bI) {
  __shared__ float As[16][68], Bs[16][68];
  int tid = threadIdx.x;
  int bh = blockIdx.z;
  int i0 = blockIdx.y * 64, j0 = blockIdx.x * 64;
  P += (size_t)bh * 65536; Q += (size_t)bh * 65536; C += (size_t)bh * 65536;
  int tm = tid >> 4, tn = tid & 15, lr = tid >> 2, lk = (tid & 3) * 4;
  int qk = tid >> 4, qj = (tid & 15) * 4;
  float acc[4][4] = {};
  for (int k0 = 0; k0 < 256; k0 += 16) {
    float4 pv = *(const float4*)&P[(size_t)(i0 + lr) * 256 + k0 + lk];
    As[lk + 0][lr] = pv.x; As[lk + 1][lr] = pv.y; As[lk + 2][lr] = pv.z; As[lk + 3][lr] = pv.w;
    float4 qv = *(const float4*)&Q[(size_t)(k0 + qk) * 256 + j0 + qj];
    int krow = k0 + qk, jc = j0 + qj;
    Bs[qk][qj + 0] = g * qv.x + (krow == jc + 0 ? bI : 0.f);
    Bs[qk][qj + 1] = g * qv.y + (krow == jc + 1 ? bI : 0.f);
    Bs[qk][qj + 2] = g * qv.z + (krow == jc + 2 ? bI : 0.f);
    Bs[qk][qj + 3] = g * qv.w + (krow == jc + 3 ? bI : 0.f);
    __syncthreads();
#pragma unroll
    for (int kk = 0; kk < 16; ++kk) FMA16();
    __syncthreads();
  }
#pragma unroll
  for (int i = 0; i < 4; ++i) {
    int ii = i0 + tm * 4 + i;
    int jj = j0 + tn * 4;
    float4 st;
    st.x = (ii == jj + 0 ? aI : 0.f) + s * acc[i][0];
    st.y = (ii == jj + 1 ? aI : 0.f) + s * acc[i][1];
    st.z = (ii == jj + 2 ? aI : 0.f) + s * acc[i][2];
    st.w = (ii == jj + 3 ? aI : 0.f) + s * acc[i][3];
    *(float4*)&C[(size_t)ii * 256 + jj] = st;
  }
}

// sim3[bh][m][n] = q_land[m] . k[n]  (NT, K=64)
__global__ __launch_bounds__(256) void k_sim3(const float* __restrict__ ql,
                                              const float* __restrict__ kmat,
                                              float* __restrict__ sim3) {
  __shared__ float As[16][68], Bs[16][68];
  int tid = threadIdx.x, bh = blockIdx.z;
  int m0 = blockIdx.y * 64, n0 = blockIdx.x * 64;
  const float* A = ql + (size_t)bh * 256 * 64;
  const float* B = kmat + (size_t)bh * 4096 * 64;
  float* Cm = sim3 + (size_t)bh * 256 * 4096;
  int tm = tid >> 4, tn = tid & 15, lr = tid >> 2, lk = (tid & 3) * 4;
  float acc[4][4] = {};
  for (int k0 = 0; k0 < 64; k0 += 16) {
    float4 av = *(const float4*)&A[(size_t)(m0 + lr) * 64 + k0 + lk];
    float4 bv = *(const float4*)&B[(size_t)(n0 + lr) * 64 + k0 + lk];
    As[lk + 0][lr] = av.x; As[lk + 1][lr] = av.y; As[lk + 2][lr] = av.z; As[lk + 3][lr] = av.w;
    Bs[lk + 0][lr] = bv.x; Bs[lk + 1][lr] = bv.y; Bs[lk + 2][lr] = bv.z; Bs[lk + 3][lr] = bv.w;
    __syncthreads();
#pragma unroll
    for (int kk = 0; kk < 16; ++kk) FMA16();
    __syncthreads();
  }
#pragma unroll
  for (int i = 0; i < 4; ++i) {
    float4 st; st.x = acc[i][0]; st.y = acc[i][1]; st.z = acc[i][2]; st.w = acc[i][3];
    *(float4*)&Cm[(size_t)(m0 + tm * 4 + i) * 4096 + n0 + tn * 4] = st;
  }
}

// in-place row softmax over 4096
__global__ __launch_bounds__(256) void k_sm4096(float* __restrict__ sim) {
  __shared__ float s4[4];
  int m = blockIdx.x, bh = blockIdx.y, tid = threadIdx.x;
  float* row = sim + ((size_t)bh * 256 + m) * 4096;
  float v[16];
  float mx = -1e30f;
#pragma unroll
  for (int i = 0; i < 16; ++i) { v[i] = row[i * 256 + tid]; mx = fmaxf(mx, v[i]); }
  mx = block_red(mx, s4, false);
  float ssum = 0;
#pragma unroll
  for (int i = 0; i < 16; ++i) { v[i] = expf(v[i] - mx); ssum += v[i]; }
  ssum = block_red(ssum, s4, true);
  float inv = 1.f / ssum;
#pragma unroll
  for (int i = 0; i < 16; ++i) row[i * 256 + tid] = v[i] * inv;
}

// a3 @ v  split-K partials  (A [256,4096] row-major, B=v [4096,64])
__global__ __launch_bounds__(256) void k_a3v(const float* __restrict__ a3,
                                             const float* __restrict__ v,
                                             float* __restrict__ part) {
  __shared__ float As[16][68], Bs[16][68];
  int tid = threadIdx.x;
  int kc = blockIdx.x, m0 = blockIdx.y * 64, bh = blockIdx.z;
  const float* A = a3 + (size_t)bh * 256 * 4096;
  const float* B = v + (size_t)bh * 4096 * 64;
  int tm = tid >> 4, tn = tid & 15, lr = tid >> 2, lk = (tid & 3) * 4;
  int qk = tid >> 4, qj = (tid & 15) * 4;
  float acc[4][4] = {};
  int kbeg = kc * 512;
  for (int k0 = kbeg; k0 < kbeg + 512; k0 += 16) {
    float4 av = *(const float4*)&A[(size_t)(m0 + lr) * 4096 + k0 + lk];
    As[lk + 0][lr] = av.x; As[lk + 1][lr] = av.y; As[lk + 2][lr] = av.z; As[lk + 3][lr] = av.w;
    float4 bv = *(const float4*)&B[(size_t)(k0 + qk) * 64 + qj];
    Bs[qk][qj + 0] = bv.x; Bs[qk][qj + 1] = bv.y; Bs[qk][qj + 2] = bv.z; Bs[qk][qj + 3] = bv.w;
    __syncthreads();
#pragma unroll
    for (int kk = 0; kk < 16; ++kk) FMA16();
    __syncthreads();
  }
#pragma unroll
  for (int i = 0; i < 4; ++i) {
    float4 st; st.x = acc[i][0]; st.y = acc[i][1]; st.z = acc[i][2]; st.w = acc[i][3];
    *(float4*)&part[(((size_t)kc * 16 + bh) * 256 + m0 + tm * 4 + i) * 64 + tn * 4] = st;
  }
}

__global__ __launch_bounds__(256) void k_a3v_red(const float* __restrict__ part,
                                                 float* __restrict__ a3v) {
  int idx = blockIdx.x * 256 + threadIdx.x;
  float s = 0;
#pragma unroll
  for (int c = 0; c < 8; ++c) s += part[(size_t)c * 262144 + idx];
  a3v[idx] = s;
}

// wm = z @ a3v  ([256,256]@[256,64])
__global__ __launch_bounds__(256) void k_wm(const float* __restrict__ z,
                                            const float* __restrict__ a3v,
                                            float* __restrict__ wm) {
  __shared__ float As[16][68], Bs[16][68];
  int tid = threadIdx.x;
  int m0 = blockIdx.y * 64, bh = blockIdx.z;
  const float* P = z + (size_t)bh * 65536;
  const float* Q = a3v + (size_t)bh * 16384;
  int tm = tid >> 4, tn = tid & 15, lr = tid >> 2, lk = (tid & 3) * 4;
  int qk = tid >> 4, qj = (tid & 15) * 4;
  float acc[4][4] = {};
  for (int k0 = 0; k0 < 256; k0 += 16) {
    float4 pv = *(const float4*)&P[(size_t)(m0 + lr) * 256 + k0 + lk];
    As[lk + 0][lr] = pv.x; As[lk + 1][lr] = pv.y; As[lk + 2][lr] = pv.z; As[lk + 3][lr] = pv.w;
    float4 qv = *(const float4*)&Q[(size_t)(k0 + qk) * 64 + qj];
    Bs[qk][qj + 0] = qv.x; Bs[qk][qj + 1] = qv.y; Bs[qk][qj + 2] = qv.z; Bs[qk][qj + 3] = qv.w;
    __syncthreads();
#pragma unroll
    for (int kk = 0; kk < 16; ++kk) FMA16();
    __syncthreads();
  }
#pragma unroll
  for (int i = 0; i < 4; ++i) {
    float4 st; st.x = acc[i][0]; st.y = acc[i][1]; st.z = acc[i][2]; st.w = acc[i][3];
    *(float4*)&wm[((size_t)bh * 256 + m0 + tm * 4 + i) * 64 + tn * 4] = st;
  }
}

// Tiled fused attention tail: per block = 64 tokens x 1 head.
// S = q_tile @ kl^T (64x256, regs) -> in-register row softmax -> out = P @ wm
// (per-64-col LDS round trip) -> + depthwise conv residual -> y.
__global__ __launch_bounds__(256) void k_fused_tile(const float* __restrict__ q,
                                                    const float* __restrict__ kl,
                                                    const float* __restrict__ wm,
                                                    const float* __restrict__ v,
                                                    const float* __restrict__ cw,
                                                    float* __restrict__ y) {
  __shared__ float smem[8704];        // A: [0,4352)=[64][68], B: [4352,8704)=[64][68]
  __shared__ float cwL[KCONV];
  float* smA = smem;
  float* smB = smem + 4352;
  const int tid = threadIdx.x;
  const int h = blockIdx.y, b = blockIdx.z;
  const int bh = b * HEADS + h;
  const int n0 = blockIdx.x * 64;
  const int tm = tid >> 4, tn = tid & 15;

  // stage q tile transposed: smA[k][r] = q[bh][n0+r][k]
  {
    int r = tid & 63, w = tid >> 6;
    const float* src = q + ((size_t)bh * 4096 + n0 + r) * 64 + w * 16;
#pragma unroll
    for (int p = 0; p < 4; ++p) {
      float4 vv = *(const float4*)&src[p * 4];
      int kk = w * 16 + p * 4;
      smA[(kk + 0) * 68 + r] = vv.x;
      smA[(kk + 1) * 68 + r] = vv.y;
      smA[(kk + 2) * 68 + r] = vv.z;
      smA[(kk + 3) * 68 + r] = vv.w;
    }
  }
  if (tid < KCONV) cwL[tid] = cw[h * KCONV + tid];

  float sacc[4][4][4] = {};   // [coltile][i][j]
#pragma unroll
  for (int c = 0; c < 4; ++c) {
    __syncthreads();
    // stage kl tile c transposed: smB[k][jl] = kl[bh][c*64+jl][k]
    {
      int jl = tid & 63, w = tid >> 6;
      const float* src = kl + ((size_t)bh * 256 + c * 64 + jl) * 64 + w * 16;
#pragma unroll
      for (int p = 0; p < 4; ++p) {
        float4 vv = *(const float4*)&src[p * 4];
        int kk = w * 16 + p * 4;
        smB[(kk + 0) * 68 + jl] = vv.x;
        smB[(kk + 1) * 68 + jl] = vv.y;
        smB[(kk + 2) * 68 + jl] = vv.z;
        smB[(kk + 3) * 68 + jl] = vv.w;
      }
    }
    __syncthreads();
#pragma unroll 1
    for (int k0 = 0; k0 < 64; k0 += 16) {
#pragma unroll
      for (int k2 = 0; k2 < 16; ++k2) {
        int kk = k0 + k2;
        float4 a_ = *(const float4*)&smA[kk * 68 + tm * 4];
        float4 b_ = *(const float4*)&smB[kk * 68 + tn * 4];
        sacc[c][0][0]+=a_.x*b_.x; sacc[c][0][1]+=a_.x*b_.y; sacc[c][0][2]+=a_.x*b_.z; sacc[c][0][3]+=a_.x*b_.w;
        sacc[c][1][0]+=a_.y*b_.x; sacc[c][1][1]+=a_.y*b_.y; sacc[c][1][2]+=a_.y*b_.z; sacc[c][1][3]+=a_.y*b_.w;
        sacc[c][2][0]+=a_.z*b_.x; sacc[c][2][1]+=a_.z*b_.y; sacc[c][2][2]+=a_.z*b_.z; sacc[c][2][3]+=a_.z*b_.w;
        sacc[c][3][0]+=a_.w*b_.x; sacc[c][3][1]+=a_.w*b_.y; sacc[c][3][2]+=a_.w*b_.z; sacc[c][3][3]+=a_.w*b_.w;
      }
    }
  }

  // in-register row softmax: row r=tm*4+i lives on the 16 lanes sharing tm
#pragma unroll
  for (int i = 0; i < 4; ++i) {
    float m_ = -1e30f;
#pragma unroll
    for (int c = 0; c < 4; ++c)
#pragma unroll
      for (int j = 0; j < 4; ++j) m_ = fmaxf(m_, sacc[c][i][j]);
#pragma unroll
    for (int o = 8; o; o >>= 1) m_ = fmaxf(m_, __shfl_xor(m_, o));
    float s_ = 0.f;
#pragma unroll
    for (int c = 0; c < 4; ++c)
#pragma unroll
      for (int j = 0; j < 4; ++j) {
        float e = expf(sacc[c][i][j] - m_);
        sacc[c][i][j] = e;
        s_ += e;
      }
#pragma unroll
    for (int o = 8; o; o >>= 1) s_ += __shfl_xor(s_, o);
    float inv_ = 1.f / s_;
#pragma unroll
    for (int c = 0; c < 4; ++c)
#pragma unroll
      for (int j = 0; j < 4; ++j) sacc[c][i][j] *= inv_;
  }

  // out = P @ wm, per column-tile via LDS
  float oacc[4][4] = {};
#pragma unroll
  for (int c = 0; c < 4; ++c) {
    __syncthreads();
    // P tile c -> smA[col][row]
#pragma unroll
    for (int j = 0; j < 4; ++j)
#pragma unroll
      for (int i = 0; i < 4; ++i)
        smA[(tn * 4 + j) * 68 + tm * 4 + i] = sacc[c][i][j];
    // wm tile c -> smB[k][d] (direct copy)
    {
      int k = tid >> 2, qq = tid & 3;
      const float* src = wm + ((size_t)bh * 256 + c * 64 + k) * 64;
#pragma unroll
      for (int p = 0; p < 4; ++p)
        *(float4*)&smB[k * 68 + 16 * p + 4 * qq] = *(const float4*)&src[16 * p + 4 * qq];
    }
    __syncthreads();
#pragma unroll 1
    for (int k0 = 0; k0 < 64; k0 += 16) {
#pragma unroll
      for (int k2 = 0; k2 < 16; ++k2) {
        int kk = k0 + k2;
        float4 a_ = *(const float4*)&smA[kk * 68 + tm * 4];
        float4 b_ = *(const float4*)&smB[kk * 68 + tn * 4];
        oacc[0][0]+=a_.x*b_.x; oacc[0][1]+=a_.x*b_.y; oacc[0][2]+=a_.x*b_.z; oacc[0][3]+=a_.x*b_.w;
        oacc[1][0]+=a_.y*b_.x; oacc[1][1]+=a_.y*b_.y; oacc[1][2]+=a_.y*b_.z; oacc[1][3]+=a_.y*b_.w;
        oacc[2][0]+=a_.z*b_.x; oacc[2][1]+=a_.z*b_.y; oacc[2][2]+=a_.z*b_.z; oacc[2][3]+=a_.z*b_.w;
        oacc[3][0]+=a_.w*b_.x; oacc[3][1]+=a_.w*b_.y; oacc[3][2]+=a_.w*b_.z; oacc[3][3]+=a_.w*b_.w;
      }
    }
  }

  // conv residual: stage v[n0-16 .. n0+79][0..63] into smem[96][68]
  __syncthreads();
  {
    int c4 = (tid & 15) * 4;
    int rbase = tid >> 4;
#pragma unroll
    for (int p = 0; p < 6; ++p) {
      int r = rbase + p * 16;
      int n = n0 - 16 + r;
      float4 vv = make_float4(0.f, 0.f, 0.f, 0.f);
      if (n >= 0 && n < 4096) vv = *(const float4*)&v[((size_t)bh * 4096 + n) * 64 + c4];
      *(float4*)&smem[r * 68 + c4] = vv;
    }
  }
  __syncthreads();
#pragma unroll
  for (int i = 0; i < 4; ++i) {
    int r = tm * 4 + i;
    float4 res = make_float4(0.f, 0.f, 0.f, 0.f);
#pragma unroll 1
    for (int t = 0; t < KCONV; ++t) {
      float w_ = cwL[t];
      float4 vv = *(const float4*)&smem[(r + t) * 68 + tn * 4];
      res.x += w_ * vv.x; res.y += w_ * vv.y; res.z += w_ * vv.z; res.w += w_ * vv.w;
    }
    float4 st;
    st.x = oacc[i][0] + res.x;
    st.y = oacc[i][1] + res.y;
    st.z = oacc[i][2] + res.z;
    st.w = oacc[i][3] + res.w;
    *(float4*)&y[((size_t)b * 4096 + n0 + r) * 512 + h * 64 + tn * 4] = st;
  }
}

// out = x + y @ out_w^T + out_b
__global__ __launch_bounds__(256) void k_outproj(const float* __restrict__ Y,
                                                 const float* __restrict__ W,
                                                 const float* __restrict__ bias,
                                                 const float* __restrict__ x,
                                                 float* __restrict__ out) {
  __shared__ float As[16][68], Bs[16][68];
  int tid = threadIdx.x;
  int m0 = blockIdx.y * 64, c0 = blockIdx.x * 64;
  int tm = tid >> 4, tn = tid & 15, lr = tid >> 2, lk = (tid & 3) * 4;
  float acc[4][4] = {};
  for (int k0 = 0; k0 < 512; k0 += 16) {
    float4 av = *(const float4*)&Y[(size_t)(m0 + lr) * 512 + k0 + lk];
    float4 bv = *(const float4*)&W[(size_t)(c0 + lr) * 512 + k0 + lk];
    As[lk + 0][lr] = av.x; As[lk + 1][lr] = av.y; As[lk + 2][lr] = av.z; As[lk + 3][lr] = av.w;
    Bs[lk + 0][lr] = bv.x; Bs[lk + 1][lr] = bv.y; Bs[lk + 2][lr] = bv.z; Bs[lk + 3][lr] = bv.w;
    __syncthreads();
#pragma unroll
    for (int kk = 0; kk < 16; ++kk) FMA16();
    __syncthreads();
  }
  float4 bb = *(const float4*)&bias[c0 + tn * 4];
#pragma unroll
  for (int i = 0; i < 4; ++i) {
    int m = m0 + tm * 4 + i;
    float4 xv = *(const float4*)&x[(size_t)m * 512 + c0 + tn * 4];
    float4 st;
    st.x = acc[i][0] + xv.x + bb.x;
    st.y = acc[i][1] + xv.y + bb.y;
    st.z = acc[i][2] + xv.z + bb.z;
    st.w = acc[i][3] + xv.w + bb.w;
    *(float4*)&out[(size_t)m * 512 + c0 + tn * 4] = st;
  }
}

// ---------------- launcher ----------------
extern "C" void kernel_launch(void* const* d_in, const int* in_sizes, int n_in,
                              void* d_out, int out_size, void* d_ws, size_t ws_size,
                              hipStream_t stream) {
  const float* x      = (const float*)d_in[0];
  const float* ln_w   = (const float*)d_in[1];
  const float* ln_b   = (const float*)d_in[2];
  const float* qkv_w  = (const float*)d_in[3];
  const float* out_w  = (const float*)d_in[4];
  const float* out_b  = (const float*)d_in[5];
  const float* conv_w = (const float*)d_in[6];
  float* wsf = (float*)d_ws;
  float* out = (float*)d_out;

  float* xn   = wsf + OFF_XN;
  float* q    = wsf + OFF_Q;
  float* k    = wsf + OFF_K;
  float* v    = wsf + OFF_V;
  float* y    = wsf + OFF_Y;
  float* ql   = wsf + OFF_QL;
  float* kl   = wsf + OFF_KL;
  float* a2   = wsf + OFF_A2;
  float* zA   = wsf + OFF_ZA;
  float* zB   = wsf + OFF_ZB;
  float* tA   = wsf + OFF_TA;
  float* tB2  = wsf + OFF_TB2;
  float* tB3  = wsf + OFF_TB3;
  float* sim3 = wsf + OFF_SIM3;
  float* a3v  = wsf + OFF_A3V;
  float* wm   = wsf + OFF_WM;
  float* part = wsf + OFF_PART;
  unsigned* scal = (unsigned*)(wsf + OFF_SCAL);

  k_init<<<1, 64, 0, stream>>>(scal);
  k_ln<<<2048, 256, 0, stream>>>(x, ln_w, ln_b, xn);
  k_qkv<<<dim3(24, 128), 256, 0, stream>>>(xn, qkv_w, q, k, v);
  k_land<<<2048, 256, 0, stream>>>(q, k, ql, kl);
  k_sim2<<<dim3(256, 16), 256, 0, stream>>>(ql, kl, a2);
  k_pinv_red<<<16, 256, 0, stream>>>(a2, scal);
  k_z0<<<4096, 256, 0, stream>>>(a2, scal, zA);

  dim3 g44(4, 4, 16);
  float* zc = zA; float* zn = zB;
  for (int it = 0; it < 6; ++it) {
    k_pg<<<g44, 256, 0, stream>>>(a2, zc, tA, 0.f, 1.f, 1.f, 0.f);     // A  = a2 @ z
    k_pg<<<g44, 256, 0, stream>>>(tA, tA, tB2, 15.f, -1.f, -1.f, 7.f); // B2 = 15I - A@(7I-A)
    k_pg<<<g44, 256, 0, stream>>>(tA, tB2, tB3, 13.f, -1.f, 1.f, 0.f); // B3 = 13I - A@B2
    k_pg<<<g44, 256, 0, stream>>>(zc, tB3, zn, 0.f, 0.25f, 1.f, 0.f);  // z  = 0.25 z@B3
    float* t = zc; zc = zn; zn = t;
  }

  k_sim3<<<dim3(64, 4, 16), 256, 0, stream>>>(ql, k, sim3);
  k_sm4096<<<dim3(256, 16), 256, 0, stream>>>(sim3);
  k_a3v<<<dim3(8, 4, 16), 256, 0, stream>>>(sim3, v, part);
  k_a3v_red<<<1024, 256, 0, stream>>>(part, a3v);
  k_wm<<<dim3(1, 4, 16), 256, 0, stream>>>(zc, a3v, wm);
  k_fused_tile<<<dim3(64, 8, 2), 256, 0, stream>>>(q, kl, wm, v, conv_w, y);
  k_outproj<<<dim3(8, 128), 256, 0, stream>>>(y, out_w, out_b, x, out);
}

// Round 3
// 680.268 us; speedup vs baseline: 2.4810x; 1.4212x over previous
//
#include <hip/hip_runtime.h>
#include <math.h>

// ---------------- problem constants ----------------
#define DIMD  512
#define NSEQ  4096
#define BATCH 2
#define HEADS 8
#define DHEAD 64
#define MLAND 256
#define BH    (BATCH*HEADS)      // 16
#define QSCALE 0.125f
#define LN_EPS 1e-5f
#define KCONV 33

typedef __attribute__((ext_vector_type(8))) short bf16x8;
typedef __attribute__((ext_vector_type(4))) float f32x4;

// ---------------- workspace layout (MB offsets) ----------------
// f32: q@0 k@16 v@32 ql@48 kl@49 a2@50 part@54 wm@62 scal@63
// bf16: xnh@64 wqh@72 owh@74 kh@76 vTh@84 qlh@92 a2h@93
//       zA@95 zAT@97 zB@99 zBT@101 Am@103 AmT@105 W2T@107 W4T@109
//       sim3h@111 a3vTh@143 yh@144   (end 152MB)
#define WB(p, mb) ((char*)(p) + (size_t)(mb) * 1048576ull)

// ---------------- helpers ----------------
__device__ __forceinline__ unsigned short f2b(float f) {
  unsigned u = __float_as_uint(f);
  return (unsigned short)((u + 0x7FFFu + ((u >> 16) & 1u)) >> 16);
}
__device__ __forceinline__ float b2f(unsigned short h) {
  return __uint_as_float(((unsigned)h) << 16);
}

__device__ __forceinline__ float block_red(float v, float* s4, bool sum) {
#pragma unroll
  for (int o = 32; o; o >>= 1) {
    float t = __shfl_xor(v, o);
    v = sum ? v + t : fmaxf(v, t);
  }
  int wid = threadIdx.x >> 6;
  if ((threadIdx.x & 63) == 0) s4[wid] = v;
  __syncthreads();
  float r = sum ? (s4[0] + s4[1] + s4[2] + s4[3])
                : fmaxf(fmaxf(s4[0], s4[1]), fmaxf(s4[2], s4[3]));
  __syncthreads();
  return r;
}

// stage ROWS x 32 bf16 tile (row-major, contiguous k) into LDS, reg-staged
template<int ROWS>
__device__ __forceinline__ void stage32(const unsigned short* __restrict__ g, int ld,
                                        short* lds, int tid) {
  const int TOT = ROWS * 4;
#pragma unroll
  for (int i = tid; i < TOT; i += 256) {
    int r = i >> 2, c = i & 3;
    *(uint4*)(lds + r * 32 + c * 8) = *(const uint4*)(g + (size_t)r * ld + c * 8);
  }
}

// wave computes 64x64 from LDS tiles As[.][32], Bs[.][32] (both [row][k] bf16)
__device__ __forceinline__ void mma_step32(const short* As, const short* Bs,
                                           int wrow, int wcol, int l, f32x4 acc[4][4]) {
  int lr = l & 15, lk = (l >> 4) * 8;
  bf16x8 af[4], bf_[4];
#pragma unroll
  for (int f = 0; f < 4; ++f) {
    af[f]  = *(const bf16x8*)&As[(wrow + f * 16 + lr) * 32 + lk];
    bf_[f] = *(const bf16x8*)&Bs[(wcol + f * 16 + lr) * 32 + lk];
  }
#pragma unroll
  for (int i = 0; i < 4; ++i)
#pragma unroll
    for (int j = 0; j < 4; ++j)
      acc[i][j] = __builtin_amdgcn_mfma_f32_16x16x32_bf16(af[i], bf_[j], acc[i][j], 0, 0, 0);
}

// ---------------- kernels ----------------

__global__ void k_init(unsigned* scal) {
  if (threadIdx.x < 2) scal[threadIdx.x] = 0u;
}

// LayerNorm -> bf16 xn
__global__ __launch_bounds__(256) void k_ln(const float* __restrict__ x,
                                            const float* __restrict__ w,
                                            const float* __restrict__ b,
                                            unsigned short* __restrict__ xnh) {
  int lane = threadIdx.x & 63;
  int row = blockIdx.x * 4 + (threadIdx.x >> 6);
  const float* xr = x + (size_t)row * DIMD;
  float4 v0 = *(const float4*)&xr[lane * 8];
  float4 v1 = *(const float4*)&xr[lane * 8 + 4];
  float s  = v0.x + v0.y + v0.z + v0.w + v1.x + v1.y + v1.z + v1.w;
  float ss = v0.x*v0.x + v0.y*v0.y + v0.z*v0.z + v0.w*v0.w
           + v1.x*v1.x + v1.y*v1.y + v1.z*v1.z + v1.w*v1.w;
#pragma unroll
  for (int o = 32; o; o >>= 1) { s += __shfl_xor(s, o); ss += __shfl_xor(ss, o); }
  float mu = s * (1.f / 512.f);
  float var = ss * (1.f / 512.f) - mu * mu;
  float rstd = rsqrtf(var + LN_EPS);
  float4 w0 = *(const float4*)&w[lane * 8];
  float4 w1 = *(const float4*)&w[lane * 8 + 4];
  float4 b0 = *(const float4*)&b[lane * 8];
  float4 b1 = *(const float4*)&b[lane * 8 + 4];
  float o0x = (v0.x - mu) * rstd * w0.x + b0.x;
  float o0y = (v0.y - mu) * rstd * w0.y + b0.y;
  float o0z = (v0.z - mu) * rstd * w0.z + b0.z;
  float o0w = (v0.w - mu) * rstd * w0.w + b0.w;
  float o1x = (v1.x - mu) * rstd * w1.x + b1.x;
  float o1y = (v1.y - mu) * rstd * w1.y + b1.y;
  float o1z = (v1.z - mu) * rstd * w1.z + b1.z;
  float o1w = (v1.w - mu) * rstd * w1.w + b1.w;
  uint4 pk;
  pk.x = (unsigned)f2b(o0x) | ((unsigned)f2b(o0y) << 16);
  pk.y = (unsigned)f2b(o0z) | ((unsigned)f2b(o0w) << 16);
  pk.z = (unsigned)f2b(o1x) | ((unsigned)f2b(o1y) << 16);
  pk.w = (unsigned)f2b(o1z) | ((unsigned)f2b(o1w) << 16);
  *(uint4*)&xnh[(size_t)row * DIMD + lane * 8] = pk;
}

// convert weights to bf16
__global__ __launch_bounds__(256) void k_wconv(const float* __restrict__ qkvw,
                                               const float* __restrict__ outw,
                                               unsigned short* __restrict__ wqh,
                                               unsigned short* __restrict__ owh) {
  int idx = blockIdx.x * 256 + threadIdx.x;
  if (idx < 786432) wqh[idx] = f2b(qkvw[idx]);
  else owh[idx - 786432] = f2b(outw[idx - 786432]);
}

// QKV: C[m,c]=sum_k xn[m,k]*W[c,k]; scatter q/k/v fp32 + kh bf16 + vT bf16
__global__ __launch_bounds__(256) void k_qkv_mfma(const unsigned short* __restrict__ xnh,
                                                  const unsigned short* __restrict__ wqh,
                                                  float* __restrict__ qf,
                                                  float* __restrict__ kf,
                                                  float* __restrict__ vf,
                                                  unsigned short* __restrict__ kh,
                                                  unsigned short* __restrict__ vTh) {
  __shared__ short As[128 * 32], Bs[128 * 32];
  int tid = threadIdx.x, l = tid & 63, wid = tid >> 6;
  int wrow = (wid >> 1) * 64, wcol = (wid & 1) * 64;
  int m0 = blockIdx.y * 128, c0 = blockIdx.x * 128;
  f32x4 acc[4][4] = {};
  for (int k0 = 0; k0 < 512; k0 += 32) {
    __syncthreads();
    stage32<128>(xnh + (size_t)m0 * 512 + k0, 512, As, tid);
    stage32<128>(wqh + (size_t)c0 * 512 + k0, 512, Bs, tid);
    __syncthreads();
    mma_step32(As, Bs, wrow, wcol, l, acc);
  }
  const int which = c0 >> 9;
#pragma unroll
  for (int i = 0; i < 4; ++i) {
#pragma unroll
    for (int j = 0; j < 4; ++j) {
      int col = c0 + wcol + j * 16 + (l & 15);
      int hh = (col >> 6) & 7, d = col & 63;
      int m_base = m0 + wrow + i * 16 + ((l >> 4) * 4);
      int bb = m_base >> 12, n0 = m_base & 4095;
      size_t hb = (size_t)(bb * 8 + hh);
      if (which == 0) {
#pragma unroll
        for (int r = 0; r < 4; ++r)
          qf[(hb * 4096 + n0 + r) * 64 + d] = acc[i][j][r] * QSCALE;
      } else if (which == 1) {
#pragma unroll
        for (int r = 0; r < 4; ++r) {
          float val = acc[i][j][r];
          kf[(hb * 4096 + n0 + r) * 64 + d] = val;
          kh[(hb * 4096 + n0 + r) * 64 + d] = f2b(val);
        }
      } else {
        ushort4 hv;
        float v0 = acc[i][j][0], v1 = acc[i][j][1], v2 = acc[i][j][2], v3 = acc[i][j][3];
#pragma unroll
        for (int r = 0; r < 4; ++r)
          vf[(hb * 4096 + n0 + r) * 64 + d] = acc[i][j][r];
        hv.x = f2b(v0); hv.y = f2b(v1); hv.z = f2b(v2); hv.w = f2b(v3);
        *(ushort4*)&vTh[(hb * 64 + d) * 4096 + n0] = hv;
      }
    }
  }
}

// landmark means (l=16); ql also bf16
__global__ __launch_bounds__(256) void k_land(const float* __restrict__ q,
                                              const float* __restrict__ k,
                                              float* __restrict__ ql,
                                              float* __restrict__ kl,
                                              unsigned short* __restrict__ qlh) {
  int idx = blockIdx.x * 256 + threadIdx.x;
  int sel = idx >= (BH * MLAND * DHEAD);
  int e = sel ? idx - BH * MLAND * DHEAD : idx;
  int bh = e >> 14; int m = (e >> 6) & 255; int d = e & 63;
  const float* src = sel ? k : q;
  size_t base = ((size_t)bh * 4096 + m * 16) * 64 + d;
  float s = 0;
#pragma unroll
  for (int t = 0; t < 16; ++t) s += src[base + t * 64];
  float val = s * (1.f / 16.f);
  (sel ? kl : ql)[e] = val;
  if (!sel) qlh[e] = f2b(val);
}

// sim2 + row softmax -> a2 fp32 + bf16
__global__ __launch_bounds__(256) void k_sim2(const float* __restrict__ ql,
                                              const float* __restrict__ kl,
                                              float* __restrict__ a2,
                                              unsigned short* __restrict__ a2h) {
  __shared__ float qs[64];
  __shared__ float s4[4];
  int i = blockIdx.x, bh = blockIdx.y, tid = threadIdx.x;
  if (tid < 16) ((float4*)qs)[tid] = ((const float4*)(ql + ((size_t)bh * 256 + i) * 64))[tid];
  __syncthreads();
  const float* kr = kl + ((size_t)bh * 256 + tid) * 64;
  float s = 0;
#pragma unroll
  for (int d = 0; d < 64; d += 4) {
    float4 kv = *(const float4*)&kr[d];
    s += qs[d] * kv.x + qs[d + 1] * kv.y + qs[d + 2] * kv.z + qs[d + 3] * kv.w;
  }
  float mx = block_red(s, s4, false);
  float p = expf(s - mx);
  float tot = block_red(p, s4, true);
  float val = p / tot;
  a2[((size_t)bh * 256 + i) * 256 + tid] = val;
  a2h[((size_t)bh * 256 + i) * 256 + tid] = f2b(val);
}

__global__ __launch_bounds__(256) void k_pinv_red(const float* __restrict__ a2,
                                                  unsigned* __restrict__ scal) {
  __shared__ float s4[4];
  int bh = blockIdx.x, tid = threadIdx.x;
  const float* m = a2 + (size_t)bh * 65536;
  float cs = 0;
  for (int i = 0; i < 256; ++i) cs += fabsf(m[(size_t)i * 256 + tid]);
  float rs = 0;
  const float* row = m + (size_t)tid * 256;
  for (int j = 0; j < 256; j += 4) {
    float4 v = *(const float4*)&row[j];
    rs += fabsf(v.x) + fabsf(v.y) + fabsf(v.z) + fabsf(v.w);
  }
  float mc = block_red(cs, s4, false);
  float mr = block_red(rs, s4, false);
  if (tid == 0) {
    atomicMax(&scal[0], __float_as_uint(mr));
    atomicMax(&scal[1], __float_as_uint(mc));
  }
}

// z0 = a2^T / (R*C) in bf16, plus transposed copy (z0T = a2/(R*C))
__global__ __launch_bounds__(256) void k_z0h(const float* __restrict__ a2,
                                             const unsigned* __restrict__ scal,
                                             unsigned short* __restrict__ zh,
                                             unsigned short* __restrict__ zTh) {
  int idx = blockIdx.x * 256 + threadIdx.x;
  float inv = 1.f / (__uint_as_float(scal[0]) * __uint_as_float(scal[1]));
  int bh = idx >> 16, r = (idx >> 8) & 255, c = idx & 255;
  zh[idx]  = f2b(a2[((size_t)bh << 16) + (c << 8) + r] * inv);
  zTh[idx] = f2b(a2[idx] * inv);
}

// batched pinv GEMM: acc = A @ (g*BsrcT + bI*I)^T-logic; writes s*acc to C and/or CT (bf16)
// Bsrc is the row-major [n][k] source for the B operand (already transposed storage)
__global__ __launch_bounds__(256) void k_pg_mfma(const unsigned short* __restrict__ A,
                                                 const unsigned short* __restrict__ Bsrc,
                                                 unsigned short* __restrict__ C,
                                                 unsigned short* __restrict__ CT,
                                                 float g, float bI, float s) {
  __shared__ short As[128 * 32], Bs[128 * 32];
  int tid = threadIdx.x, l = tid & 63, wid = tid >> 6;
  int wrow = (wid >> 1) * 64, wcol = (wid & 1) * 64;
  int bh = blockIdx.z;
  int i0 = blockIdx.y * 128, j0 = blockIdx.x * 128;
  A += (size_t)bh * 65536; Bsrc += (size_t)bh * 65536;
  f32x4 acc[4][4] = {};
  for (int k0 = 0; k0 < 256; k0 += 32) {
    __syncthreads();
    stage32<128>(A + (size_t)i0 * 256 + k0, 256, As, tid);
#pragma unroll
    for (int t = tid; t < 512; t += 256) {
      int r = t >> 2, c = t & 3;
      uint4 vv = *(const uint4*)(Bsrc + (size_t)(j0 + r) * 256 + k0 + c * 8);
      unsigned short* e = (unsigned short*)&vv;
      int n = j0 + r, kb = k0 + c * 8;
#pragma unroll
      for (int q = 0; q < 8; ++q) {
        float f = b2f(e[q]) * g + ((n == kb + q) ? bI : 0.f);
        e[q] = f2b(f);
      }
      *(uint4*)(Bs + r * 32 + c * 8) = vv;
    }
    __syncthreads();
    mma_step32(As, Bs, wrow, wcol, l, acc);
  }
#pragma unroll
  for (int i = 0; i < 4; ++i)
#pragma unroll
    for (int j = 0; j < 4; ++j) {
      int col = j0 + wcol + j * 16 + (l & 15);
      int row0 = i0 + wrow + i * 16 + (l >> 4) * 4;
      float v0 = acc[i][j][0] * s, v1 = acc[i][j][1] * s;
      float v2 = acc[i][j][2] * s, v3 = acc[i][j][3] * s;
      ushort4 hv; hv.x = f2b(v0); hv.y = f2b(v1); hv.z = f2b(v2); hv.w = f2b(v3);
      if (CT) *(ushort4*)&CT[(size_t)bh * 65536 + (size_t)col * 256 + row0] = hv;
      if (C) {
        unsigned short* cb = C + (size_t)bh * 65536 + (size_t)row0 * 256 + col;
        cb[0] = hv.x; cb[256] = hv.y; cb[512] = hv.z; cb[768] = hv.w;
      }
    }
}

// sim3 = q_land @ k^T -> bf16 [bh][256][4096]
__global__ __launch_bounds__(256) void k_sim3_mfma(const unsigned short* __restrict__ qlh,
                                                   const unsigned short* __restrict__ kh,
                                                   unsigned short* __restrict__ sim3h) {
  __shared__ short As[128 * 32], Bs[128 * 32];
  int tid = threadIdx.x, l = tid & 63, wid = tid >> 6;
  int wrow = (wid >> 1) * 64, wcol = (wid & 1) * 64;
  int bh = blockIdx.z;
  int m0 = blockIdx.y * 128, n0 = blockIdx.x * 128;
  const unsigned short* A = qlh + (size_t)bh * 256 * 64;
  const unsigned short* B = kh + (size_t)bh * 4096 * 64;
  f32x4 acc[4][4] = {};
  for (int k0 = 0; k0 < 64; k0 += 32) {
    __syncthreads();
    stage32<128>(A + (size_t)m0 * 64 + k0, 64, As, tid);
    stage32<128>(B + (size_t)n0 * 64 + k0, 64, Bs, tid);
    __syncthreads();
    mma_step32(As, Bs, wrow, wcol, l, acc);
  }
  unsigned short* Cm = sim3h + (size_t)bh * 1048576;
#pragma unroll
  for (int i = 0; i < 4; ++i)
#pragma unroll
    for (int j = 0; j < 4; ++j) {
      int col = n0 + wcol + j * 16 + (l & 15);
      int row0 = m0 + wrow + i * 16 + (l >> 4) * 4;
#pragma unroll
      for (int r = 0; r < 4; ++r)
        Cm[(size_t)(row0 + r) * 4096 + col] = f2b(acc[i][j][r]);
    }
}

// in-place row softmax over 4096 (bf16)
__global__ __launch_bounds__(256) void k_sm4096h(unsigned short* __restrict__ sim) {
  __shared__ float s4[4];
  int m = blockIdx.x, bh = blockIdx.y, tid = threadIdx.x;
  unsigned short* row = sim + ((size_t)bh * 256 + m) * 4096;
  float v[16];
  float mx = -1e30f;
#pragma unroll
  for (int i = 0; i < 16; ++i) { v[i] = b2f(row[i * 256 + tid]); mx = fmaxf(mx, v[i]); }
  mx = block_red(mx, s4, false);
  float ssum = 0;
#pragma unroll
  for (int i = 0; i < 16; ++i) { v[i] = expf(v[i] - mx); ssum += v[i]; }
  ssum = block_red(ssum, s4, true);
  float inv = 1.f / ssum;
#pragma unroll
  for (int i = 0; i < 16; ++i) row[i * 256 + tid] = f2b(v[i] * inv);
}

// a3 @ v split-K: BM=256,BN=64, per kc chunk of 512
__global__ __launch_bounds__(256) void k_a3v_mfma(const unsigned short* __restrict__ a3h,
                                                  const unsigned short* __restrict__ vTh,
                                                  float* __restrict__ part) {
  __shared__ short As[256 * 32], Bs[64 * 32];
  int tid = threadIdx.x, l = tid & 63, wid = tid >> 6;
  int wrow = wid * 64, wcol = 0;
  int kc = blockIdx.x, bh = blockIdx.z;
  const unsigned short* A = a3h + (size_t)bh * 1048576 + kc * 512;
  const unsigned short* B = vTh + (size_t)bh * 262144 + kc * 512;
  f32x4 acc[4][4] = {};
  for (int k0 = 0; k0 < 512; k0 += 32) {
    __syncthreads();
    stage32<256>(A + k0, 4096, As, tid);
    stage32<64>(B + k0, 4096, Bs, tid);
    __syncthreads();
    mma_step32(As, Bs, wrow, wcol, l, acc);
  }
  float* P = part + ((size_t)(kc * 16 + bh)) * 16384;
#pragma unroll
  for (int i = 0; i < 4; ++i)
#pragma unroll
    for (int j = 0; j < 4; ++j) {
      int col = j * 16 + (l & 15);
      int row0 = wrow + i * 16 + (l >> 4) * 4;
#pragma unroll
      for (int r = 0; r < 4; ++r)
        P[(size_t)(row0 + r) * 64 + col] = acc[i][j][r];
    }
}

// reduce split-K partials -> a3vT bf16 [bh][64][256]
__global__ __launch_bounds__(256) void k_a3v_redT(const float* __restrict__ part,
                                                  unsigned short* __restrict__ a3vT) {
  int idx = blockIdx.x * 256 + threadIdx.x;   // 262144
  int m = idx & 255, d = (idx >> 8) & 63, bh = idx >> 14;
  float s = 0;
#pragma unroll
  for (int c = 0; c < 8; ++c) s += part[((size_t)(c * 16 + bh) * 256 + m) * 64 + d];
  a3vT[idx] = f2b(s);
}

// wm = z @ a3v : BM=256, BN=64, K=256 -> fp32
__global__ __launch_bounds__(256) void k_wm_mfma(const unsigned short* __restrict__ zh,
                                                 const unsigned short* __restrict__ a3vTh,
                                                 float* __restrict__ wm) {
  __shared__ short As[256 * 32], Bs[64 * 32];
  int tid = threadIdx.x, l = tid & 63, wid = tid >> 6;
  int wrow = wid * 64, wcol = 0;
  int bh = blockIdx.z;
  const unsigned short* A = zh + (size_t)bh * 65536;
  const unsigned short* B = a3vTh + (size_t)bh * 16384;
  f32x4 acc[4][4] = {};
  for (int k0 = 0; k0 < 256; k0 += 32) {
    __syncthreads();
    stage32<256>(A + k0, 256, As, tid);
    stage32<64>(B + k0, 256, Bs, tid);
    __syncthreads();
    mma_step32(As, Bs, wrow, wcol, l, acc);
  }
  float* W = wm + (size_t)bh * 16384;
#pragma unroll
  for (int i = 0; i < 4; ++i)
#pragma unroll
    for (int j = 0; j < 4; ++j) {
      int col = j * 16 + (l & 15);
      int row0 = wrow + i * 16 + (l >> 4) * 4;
#pragma unroll
      for (int r = 0; r < 4; ++r)
        W[(size_t)(row0 + r) * 64 + col] = acc[i][j][r];
    }
}

// fused attention tail (f32), y emitted bf16
__global__ __launch_bounds__(256) void k_fused_tile(const float* __restrict__ q,
                                                    const float* __restrict__ kl,
                                                    const float* __restrict__ wm,
                                                    const float* __restrict__ v,
                                                    const float* __restrict__ cw,
                                                    unsigned short* __restrict__ yh) {
  __shared__ float smem[8704];
  __shared__ float cwL[KCONV];
  float* smA = smem;
  float* smB = smem + 4352;
  const int tid = threadIdx.x;
  const int h = blockIdx.y, b = blockIdx.z;
  const int bh = b * HEADS + h;
  const int n0 = blockIdx.x * 64;
  const int tm = tid >> 4, tn = tid & 15;

  {
    int r = tid & 63, w = tid >> 6;
    const float* src = q + ((size_t)bh * 4096 + n0 + r) * 64 + w * 16;
#pragma unroll
    for (int p = 0; p < 4; ++p) {
      float4 vv = *(const float4*)&src[p * 4];
      int kk = w * 16 + p * 4;
      smA[(kk + 0) * 68 + r] = vv.x;
      smA[(kk + 1) * 68 + r] = vv.y;
      smA[(kk + 2) * 68 + r] = vv.z;
      smA[(kk + 3) * 68 + r] = vv.w;
    }
  }
  if (tid < KCONV) cwL[tid] = cw[h * KCONV + tid];

  float sacc[4][4][4] = {};
#pragma unroll
  for (int c = 0; c < 4; ++c) {
    __syncthreads();
    {
      int jl = tid & 63, w = tid >> 6;
      const float* src = kl + ((size_t)bh * 256 + c * 64 + jl) * 64 + w * 16;
#pragma unroll
      for (int p = 0; p < 4; ++p) {
        float4 vv = *(const float4*)&src[p * 4];
        int kk = w * 16 + p * 4;
        smB[(kk + 0) * 68 + jl] = vv.x;
        smB[(kk + 1) * 68 + jl] = vv.y;
        smB[(kk + 2) * 68 + jl] = vv.z;
        smB[(kk + 3) * 68 + jl] = vv.w;
      }
    }
    __syncthreads();
#pragma unroll 1
    for (int k0 = 0; k0 < 64; k0 += 16) {
#pragma unroll
      for (int k2 = 0; k2 < 16; ++k2) {
        int kk = k0 + k2;
        float4 a_ = *(const float4*)&smA[kk * 68 + tm * 4];
        float4 b_ = *(const float4*)&smB[kk * 68 + tn * 4];
        sacc[c][0][0]+=a_.x*b_.x; sacc[c][0][1]+=a_.x*b_.y; sacc[c][0][2]+=a_.x*b_.z; sacc[c][0][3]+=a_.x*b_.w;
        sacc[c][1][0]+=a_.y*b_.x; sacc[c][1][1]+=a_.y*b_.y; sacc[c][1][2]+=a_.y*b_.z; sacc[c][1][3]+=a_.y*b_.w;
        sacc[c][2][0]+=a_.z*b_.x; sacc[c][2][1]+=a_.z*b_.y; sacc[c][2][2]+=a_.z*b_.z; sacc[c][2][3]+=a_.z*b_.w;
        sacc[c][3][0]+=a_.w*b_.x; sacc[c][3][1]+=a_.w*b_.y; sacc[c][3][2]+=a_.w*b_.z; sacc[c][3][3]+=a_.w*b_.w;
      }
    }
  }

#pragma unroll
  for (int i = 0; i < 4; ++i) {
    float m_ = -1e30f;
#pragma unroll
    for (int c = 0; c < 4; ++c)
#pragma unroll
      for (int j = 0; j < 4; ++j) m_ = fmaxf(m_, sacc[c][i][j]);
#pragma unroll
    for (int o = 8; o; o >>= 1) m_ = fmaxf(m_, __shfl_xor(m_, o));
    float s_ = 0.f;
#pragma unroll
    for (int c = 0; c < 4; ++c)
#pragma unroll
      for (int j = 0; j < 4; ++j) {
        float e = expf(sacc[c][i][j] - m_);
        sacc[c][i][j] = e;
        s_ += e;
      }
#pragma unroll
    for (int o = 8; o; o >>= 1) s_ += __shfl_xor(s_, o);
    float inv_ = 1.f / s_;
#pragma unroll
    for (int c = 0; c < 4; ++c)
#pragma unroll
      for (int j = 0; j < 4; ++j) sacc[c][i][j] *= inv_;
  }

  float oacc[4][4] = {};
#pragma unroll
  for (int c = 0; c < 4; ++c) {
    __syncthreads();
#pragma unroll
    for (int j = 0; j < 4; ++j)
#pragma unroll
      for (int i = 0; i < 4; ++i)
        smA[(tn * 4 + j) * 68 + tm * 4 + i] = sacc[c][i][j];
    {
      int k = tid >> 2, qq = tid & 3;
      const float* src = wm + ((size_t)bh * 256 + c * 64 + k) * 64;
#pragma unroll
      for (int p = 0; p < 4; ++p)
        *(float4*)&smB[k * 68 + 16 * p + 4 * qq] = *(const float4*)&src[16 * p + 4 * qq];
    }
    __syncthreads();
#pragma unroll 1
    for (int k0 = 0; k0 < 64; k0 += 16) {
#pragma unroll
      for (int k2 = 0; k2 < 16; ++k2) {
        int kk = k0 + k2;
        float4 a_ = *(const float4*)&smA[kk * 68 + tm * 4];
        float4 b_ = *(const float4*)&smB[kk * 68 + tn * 4];
        oacc[0][0]+=a_.x*b_.x; oacc[0][1]+=a_.x*b_.y; oacc[0][2]+=a_.x*b_.z; oacc[0][3]+=a_.x*b_.w;
        oacc[1][0]+=a_.y*b_.x; oacc[1][1]+=a_.y*b_.y; oacc[1][2]+=a_.y*b_.z; oacc[1][3]+=a_.y*b_.w;
        oacc[2][0]+=a_.z*b_.x; oacc[2][1]+=a_.z*b_.y; oacc[2][2]+=a_.z*b_.z; oacc[2][3]+=a_.z*b_.w;
        oacc[3][0]+=a_.w*b_.x; oacc[3][1]+=a_.w*b_.y; oacc[3][2]+=a_.w*b_.z; oacc[3][3]+=a_.w*b_.w;
      }
    }
  }

  __syncthreads();
  {
    int c4 = (tid & 15) * 4;
    int rbase = tid >> 4;
#pragma unroll
    for (int p = 0; p < 6; ++p) {
      int r = rbase + p * 16;
      int n = n0 - 16 + r;
      float4 vv = make_float4(0.f, 0.f, 0.f, 0.f);
      if (n >= 0 && n < 4096) vv = *(const float4*)&v[((size_t)bh * 4096 + n) * 64 + c4];
      *(float4*)&smem[r * 68 + c4] = vv;
    }
  }
  __syncthreads();
#pragma unroll
  for (int i = 0; i < 4; ++i) {
    int r = tm * 4 + i;
    float4 res = make_float4(0.f, 0.f, 0.f, 0.f);
#pragma unroll 1
    for (int t = 0; t < KCONV; ++t) {
      float w_ = cwL[t];
      float4 vv = *(const float4*)&smem[(r + t) * 68 + tn * 4];
      res.x += w_ * vv.x; res.y += w_ * vv.y; res.z += w_ * vv.z; res.w += w_ * vv.w;
    }
    ushort4 st4;
    st4.x = f2b(oacc[i][0] + res.x);
    st4.y = f2b(oacc[i][1] + res.y);
    st4.z = f2b(oacc[i][2] + res.z);
    st4.w = f2b(oacc[i][3] + res.w);
    *(ushort4*)&yh[((size_t)b * 4096 + n0 + r) * 512 + h * 64 + tn * 4] = st4;
  }
}

// out = x + y @ out_w^T + out_b  (MFMA)
__global__ __launch_bounds__(256) void k_outproj_mfma(const unsigned short* __restrict__ yh,
                                                      const unsigned short* __restrict__ owh,
                                                      const float* __restrict__ bias,
                                                      const float* __restrict__ x,
                                                      float* __restrict__ out) {
  __shared__ short As[128 * 32], Bs[128 * 32];
  int tid = threadIdx.x, l = tid & 63, wid = tid >> 6;
  int wrow = (wid >> 1) * 64, wcol = (wid & 1) * 64;
  int m0 = blockIdx.y * 128, c0 = blockIdx.x * 128;
  f32x4 acc[4][4] = {};
  for (int k0 = 0; k0 < 512; k0 += 32) {
    __syncthreads();
    stage32<128>(yh + (size_t)m0 * 512 + k0, 512, As, tid);
    stage32<128>(owh + (size_t)c0 * 512 + k0, 512, Bs, tid);
    __syncthreads();
    mma_step32(As, Bs, wrow, wcol, l, acc);
  }
#pragma unroll
  for (int i = 0; i < 4; ++i)
#pragma unroll
    for (int j = 0; j < 4; ++j) {
      int col = c0 + wcol + j * 16 + (l & 15);
      int row0 = m0 + wrow + i * 16 + (l >> 4) * 4;
      float bb = bias[col];
#pragma unroll
      for (int r = 0; r < 4; ++r) {
        size_t o = (size_t)(row0 + r) * 512 + col;
        out[o] = acc[i][j][r] + x[o] + bb;
      }
    }
}

// ---------------- launcher ----------------
extern "C" void kernel_launch(void* const* d_in, const int* in_sizes, int n_in,
                              void* d_out, int out_size, void* d_ws, size_t ws_size,
                              hipStream_t stream) {
  const float* x      = (const float*)d_in[0];
  const float* ln_w   = (const float*)d_in[1];
  const float* ln_b   = (const float*)d_in[2];
  const float* qkv_w  = (const float*)d_in[3];
  const float* out_w  = (const float*)d_in[4];
  const float* out_b  = (const float*)d_in[5];
  const float* conv_w = (const float*)d_in[6];
  float* out = (float*)d_out;

  float* qf   = (float*)WB(d_ws, 0);
  float* kf   = (float*)WB(d_ws, 16);
  float* vf   = (float*)WB(d_ws, 32);
  float* ql   = (float*)WB(d_ws, 48);
  float* kl   = (float*)WB(d_ws, 49);
  float* a2   = (float*)WB(d_ws, 50);
  float* part = (float*)WB(d_ws, 54);
  float* wm   = (float*)WB(d_ws, 62);
  unsigned* scal = (unsigned*)WB(d_ws, 63);
  unsigned short* xnh  = (unsigned short*)WB(d_ws, 64);
  unsigned short* wqh  = (unsigned short*)WB(d_ws, 72);
  unsigned short* owh  = (unsigned short*)WB(d_ws, 74);
  unsigned short* kh   = (unsigned short*)WB(d_ws, 76);
  unsigned short* vTh  = (unsigned short*)WB(d_ws, 84);
  unsigned short* qlh  = (unsigned short*)WB(d_ws, 92);
  unsigned short* a2h  = (unsigned short*)WB(d_ws, 93);
  unsigned short* zA   = (unsigned short*)WB(d_ws, 95);
  unsigned short* zAT  = (unsigned short*)WB(d_ws, 97);
  unsigned short* zB   = (unsigned short*)WB(d_ws, 99);
  unsigned short* zBT  = (unsigned short*)WB(d_ws, 101);
  unsigned short* Am   = (unsigned short*)WB(d_ws, 103);
  unsigned short* AmT  = (unsigned short*)WB(d_ws, 105);
  unsigned short* W2T  = (unsigned short*)WB(d_ws, 107);
  unsigned short* W4T  = (unsigned short*)WB(d_ws, 109);
  unsigned short* sim3h= (unsigned short*)WB(d_ws, 111);
  unsigned short* a3vTh= (unsigned short*)WB(d_ws, 143);
  unsigned short* yh   = (unsigned short*)WB(d_ws, 144);

  k_init<<<1, 64, 0, stream>>>(scal);
  k_ln<<<2048, 256, 0, stream>>>(x, ln_w, ln_b, xnh);
  k_wconv<<<4096, 256, 0, stream>>>(qkv_w, out_w, wqh, owh);
  k_qkv_mfma<<<dim3(12, 64), 256, 0, stream>>>(xnh, wqh, qf, kf, vf, kh, vTh);
  k_land<<<2048, 256, 0, stream>>>(qf, kf, ql, kl, qlh);
  k_sim2<<<dim3(256, 16), 256, 0, stream>>>(ql, kl, a2, a2h);
  k_pinv_red<<<16, 256, 0, stream>>>(a2, scal);
  k_z0h<<<4096, 256, 0, stream>>>(a2, scal, zA, zAT);

  unsigned short *zc = zA, *zcT = zAT, *zn = zB, *znT = zBT;
  dim3 gpg(2, 2, 16);
  for (int it = 0; it < 6; ++it) {
    k_pg_mfma<<<gpg, 256, 0, stream>>>(a2h, zcT, Am, AmT, 1.f, 0.f, 1.f);
    k_pg_mfma<<<gpg, 256, 0, stream>>>(Am, AmT, (unsigned short*)nullptr, W2T, -1.f, 7.f, 1.f);
    k_pg_mfma<<<gpg, 256, 0, stream>>>(Am, W2T, (unsigned short*)nullptr, W4T, -1.f, 15.f, 1.f);
    k_pg_mfma<<<gpg, 256, 0, stream>>>(zc, W4T, zn, znT, -1.f, 13.f, 0.25f);
    unsigned short* t;
    t = zc; zc = zn; zn = t;
    t = zcT; zcT = znT; znT = t;
  }

  k_sim3_mfma<<<dim3(32, 2, 16), 256, 0, stream>>>(qlh, kh, sim3h);
  k_sm4096h<<<dim3(256, 16), 256, 0, stream>>>(sim3h);
  k_a3v_mfma<<<dim3(8, 1, 16), 256, 0, stream>>>(sim3h, vTh, part);
  k_a3v_redT<<<1024, 256, 0, stream>>>(part, a3vTh);
  k_wm_mfma<<<dim3(1, 1, 16), 256, 0, stream>>>(zc, a3vTh, wm);
  k_fused_tile<<<dim3(64, 8, 2), 256, 0, stream>>>(qf, kl, wm, vf, conv_w, yh);
  k_outproj_mfma<<<dim3(4, 64), 256, 0, stream>>>(yh, owh, out_b, x, out);
}

// Round 5
// 568.989 us; speedup vs baseline: 2.9662x; 1.1956x over previous
//
#include <hip/hip_runtime.h>
#include <math.h>

// ---------------- problem constants ----------------
#define DIMD  512
#define NSEQ  4096
#define BATCH 2
#define HEADS 8
#define DHEAD 64
#define MLAND 256
#define BH    (BATCH*HEADS)      // 16
#define QSCALE 0.125f
#define LN_EPS 1e-5f
#define KCONV 33

typedef __attribute__((ext_vector_type(8))) short bf16x8;
typedef __attribute__((ext_vector_type(4))) float f32x4;

// ---------------- workspace layout (MB offsets) ----------------
#define WB(p, mb) ((char*)(p) + (size_t)(mb) * 1048576ull)

// ---------------- helpers ----------------
__device__ __forceinline__ unsigned short f2b(float f) {
  unsigned u = __float_as_uint(f);
  return (unsigned short)((u + 0x7FFFu + ((u >> 16) & 1u)) >> 16);
}
__device__ __forceinline__ float b2f(unsigned short h) {
  return __uint_as_float(((unsigned)h) << 16);
}

__device__ __forceinline__ float block_red(float v, float* s4, bool sum) {
#pragma unroll
  for (int o = 32; o; o >>= 1) {
    float t = __shfl_xor(v, o);
    v = sum ? v + t : fmaxf(v, t);
  }
  int wid = threadIdx.x >> 6;
  if ((threadIdx.x & 63) == 0) s4[wid] = v;
  __syncthreads();
  float r = sum ? (s4[0] + s4[1] + s4[2] + s4[3])
                : fmaxf(fmaxf(s4[0], s4[1]), fmaxf(s4[2], s4[3]));
  __syncthreads();
  return r;
}

// stage ROWS x 32 bf16 tile (row-major, contiguous k) into LDS, reg-staged
template<int ROWS>
__device__ __forceinline__ void stage32(const unsigned short* __restrict__ g, int ld,
                                        short* lds, int tid) {
  const int TOT = ROWS * 4;
#pragma unroll
  for (int i = tid; i < TOT; i += 256) {
    int r = i >> 2, c = i & 3;
    *(uint4*)(lds + r * 32 + c * 8) = *(const uint4*)(g + (size_t)r * ld + c * 8);
  }
}

// wave computes 64x64 from LDS tiles As[.][32], Bs[.][32] (both [row][k] bf16)
__device__ __forceinline__ void mma_step32(const short* As, const short* Bs,
                                           int wrow, int wcol, int l, f32x4 acc[4][4]) {
  int lr = l & 15, lk = (l >> 4) * 8;
  bf16x8 af[4], bf_[4];
#pragma unroll
  for (int f = 0; f < 4; ++f) {
    af[f]  = *(const bf16x8*)&As[(wrow + f * 16 + lr) * 32 + lk];
    bf_[f] = *(const bf16x8*)&Bs[(wcol + f * 16 + lr) * 32 + lk];
  }
#pragma unroll
  for (int i = 0; i < 4; ++i)
#pragma unroll
    for (int j = 0; j < 4; ++j)
      acc[i][j] = __builtin_amdgcn_mfma_f32_16x16x32_bf16(af[i], bf_[j], acc[i][j], 0, 0, 0);
}

// ---------------- kernels ----------------

__global__ void k_init(unsigned* scal) {
  if (threadIdx.x < 2) scal[threadIdx.x] = 0u;
}

// LayerNorm -> bf16 xn
__global__ __launch_bounds__(256) void k_ln(const float* __restrict__ x,
                                            const float* __restrict__ w,
                                            const float* __restrict__ b,
                                            unsigned short* __restrict__ xnh) {
  int lane = threadIdx.x & 63;
  int row = blockIdx.x * 4 + (threadIdx.x >> 6);
  const float* xr = x + (size_t)row * DIMD;
  float4 v0 = *(const float4*)&xr[lane * 8];
  float4 v1 = *(const float4*)&xr[lane * 8 + 4];
  float s  = v0.x + v0.y + v0.z + v0.w + v1.x + v1.y + v1.z + v1.w;
  float ss = v0.x*v0.x + v0.y*v0.y + v0.z*v0.z + v0.w*v0.w
           + v1.x*v1.x + v1.y*v1.y + v1.z*v1.z + v1.w*v1.w;
#pragma unroll
  for (int o = 32; o; o >>= 1) { s += __shfl_xor(s, o); ss += __shfl_xor(ss, o); }
  float mu = s * (1.f / 512.f);
  float var = ss * (1.f / 512.f) - mu * mu;
  float rstd = rsqrtf(var + LN_EPS);
  float4 w0 = *(const float4*)&w[lane * 8];
  float4 w1 = *(const float4*)&w[lane * 8 + 4];
  float4 b0 = *(const float4*)&b[lane * 8];
  float4 b1 = *(const float4*)&b[lane * 8 + 4];
  float o0x = (v0.x - mu) * rstd * w0.x + b0.x;
  float o0y = (v0.y - mu) * rstd * w0.y + b0.y;
  float o0z = (v0.z - mu) * rstd * w0.z + b0.z;
  float o0w = (v0.w - mu) * rstd * w0.w + b0.w;
  float o1x = (v1.x - mu) * rstd * w1.x + b1.x;
  float o1y = (v1.y - mu) * rstd * w1.y + b1.y;
  float o1z = (v1.z - mu) * rstd * w1.z + b1.z;
  float o1w = (v1.w - mu) * rstd * w1.w + b1.w;
  uint4 pk;
  pk.x = (unsigned)f2b(o0x) | ((unsigned)f2b(o0y) << 16);
  pk.y = (unsigned)f2b(o0z) | ((unsigned)f2b(o0w) << 16);
  pk.z = (unsigned)f2b(o1x) | ((unsigned)f2b(o1y) << 16);
  pk.w = (unsigned)f2b(o1z) | ((unsigned)f2b(o1w) << 16);
  *(uint4*)&xnh[(size_t)row * DIMD + lane * 8] = pk;
}

// convert weights to bf16
__global__ __launch_bounds__(256) void k_wconv(const float* __restrict__ qkvw,
                                               const float* __restrict__ outw,
                                               unsigned short* __restrict__ wqh,
                                               unsigned short* __restrict__ owh) {
  int idx = blockIdx.x * 256 + threadIdx.x;
  if (idx < 786432) wqh[idx] = f2b(qkvw[idx]);
  else owh[idx - 786432] = f2b(outw[idx - 786432]);
}

// QKV: C[m,c]=sum_k xn[m,k]*W[c,k]; scatter q/k/v fp32 + qh/kh bf16 + vT bf16
__global__ __launch_bounds__(256) void k_qkv_mfma(const unsigned short* __restrict__ xnh,
                                                  const unsigned short* __restrict__ wqh,
                                                  float* __restrict__ qf,
                                                  float* __restrict__ kf,
                                                  float* __restrict__ vf,
                                                  unsigned short* __restrict__ qh,
                                                  unsigned short* __restrict__ kh,
                                                  unsigned short* __restrict__ vTh) {
  __shared__ short As[128 * 32], Bs[128 * 32];
  int tid = threadIdx.x, l = tid & 63, wid = tid >> 6;
  int wrow = (wid >> 1) * 64, wcol = (wid & 1) * 64;
  int m0 = blockIdx.y * 128, c0 = blockIdx.x * 128;
  f32x4 acc[4][4] = {};
  for (int k0 = 0; k0 < 512; k0 += 32) {
    __syncthreads();
    stage32<128>(xnh + (size_t)m0 * 512 + k0, 512, As, tid);
    stage32<128>(wqh + (size_t)c0 * 512 + k0, 512, Bs, tid);
    __syncthreads();
    mma_step32(As, Bs, wrow, wcol, l, acc);
  }
  const int which = c0 >> 9;
#pragma unroll
  for (int i = 0; i < 4; ++i) {
#pragma unroll
    for (int j = 0; j < 4; ++j) {
      int col = c0 + wcol + j * 16 + (l & 15);
      int hh = (col >> 6) & 7, d = col & 63;
      int m_base = m0 + wrow + i * 16 + ((l >> 4) * 4);
      int bb = m_base >> 12, n0 = m_base & 4095;
      size_t hb = (size_t)(bb * 8 + hh);
      if (which == 0) {
#pragma unroll
        for (int r = 0; r < 4; ++r) {
          float val = acc[i][j][r] * QSCALE;
          qf[(hb * 4096 + n0 + r) * 64 + d] = val;
          qh[(hb * 4096 + n0 + r) * 64 + d] = f2b(val);
        }
      } else if (which == 1) {
#pragma unroll
        for (int r = 0; r < 4; ++r) {
          float val = acc[i][j][r];
          kf[(hb * 4096 + n0 + r) * 64 + d] = val;
          kh[(hb * 4096 + n0 + r) * 64 + d] = f2b(val);
        }
      } else {
        ushort4 hv;
#pragma unroll
        for (int r = 0; r < 4; ++r)
          vf[(hb * 4096 + n0 + r) * 64 + d] = acc[i][j][r];
        hv.x = f2b(acc[i][j][0]); hv.y = f2b(acc[i][j][1]);
        hv.z = f2b(acc[i][j][2]); hv.w = f2b(acc[i][j][3]);
        *(ushort4*)&vTh[(hb * 64 + d) * 4096 + n0] = hv;
      }
    }
  }
}

// landmark means (l=16); ql,kl also bf16
__global__ __launch_bounds__(256) void k_land(const float* __restrict__ q,
                                              const float* __restrict__ k,
                                              float* __restrict__ ql,
                                              float* __restrict__ kl,
                                              unsigned short* __restrict__ qlh,
                                              unsigned short* __restrict__ klh) {
  int idx = blockIdx.x * 256 + threadIdx.x;
  int sel = idx >= (BH * MLAND * DHEAD);
  int e = sel ? idx - BH * MLAND * DHEAD : idx;
  int bh = e >> 14; int m = (e >> 6) & 255; int d = e & 63;
  const float* src = sel ? k : q;
  size_t base = ((size_t)bh * 4096 + m * 16) * 64 + d;
  float s = 0;
#pragma unroll
  for (int t = 0; t < 16; ++t) s += src[base + t * 64];
  float val = s * (1.f / 16.f);
  (sel ? kl : ql)[e] = val;
  (sel ? klh : qlh)[e] = f2b(val);
}

// sim2 + row softmax -> a2 fp32 + bf16
__global__ __launch_bounds__(256) void k_sim2(const float* __restrict__ ql,
                                              const float* __restrict__ kl,
                                              float* __restrict__ a2,
                                              unsigned short* __restrict__ a2h) {
  __shared__ float qs[64];
  __shared__ float s4[4];
  int i = blockIdx.x, bh = blockIdx.y, tid = threadIdx.x;
  if (tid < 16) ((float4*)qs)[tid] = ((const float4*)(ql + ((size_t)bh * 256 + i) * 64))[tid];
  __syncthreads();
  const float* kr = kl + ((size_t)bh * 256 + tid) * 64;
  float s = 0;
#pragma unroll
  for (int d = 0; d < 64; d += 4) {
    float4 kv = *(const float4*)&kr[d];
    s += qs[d] * kv.x + qs[d + 1] * kv.y + qs[d + 2] * kv.z + qs[d + 3] * kv.w;
  }
  float mx = block_red(s, s4, false);
  float p = expf(s - mx);
  float tot = block_red(p, s4, true);
  float val = p / tot;
  a2[((size_t)bh * 256 + i) * 256 + tid] = val;
  a2h[((size_t)bh * 256 + i) * 256 + tid] = f2b(val);
}

__global__ __launch_bounds__(256) void k_pinv_red(const float* __restrict__ a2,
                                                  unsigned* __restrict__ scal) {
  __shared__ float s4[4];
  int bh = blockIdx.x, tid = threadIdx.x;
  const float* m = a2 + (size_t)bh * 65536;
  float cs = 0;
  for (int i = 0; i < 256; ++i) cs += fabsf(m[(size_t)i * 256 + tid]);
  float rs = 0;
  const float* row = m + (size_t)tid * 256;
  for (int j = 0; j < 256; j += 4) {
    float4 v = *(const float4*)&row[j];
    rs += fabsf(v.x) + fabsf(v.y) + fabsf(v.z) + fabsf(v.w);
  }
  float mc = block_red(cs, s4, false);
  float mr = block_red(rs, s4, false);
  if (tid == 0) {
    atomicMax(&scal[0], __float_as_uint(mr));
    atomicMax(&scal[1], __float_as_uint(mc));
  }
}

// z0 = a2^T / (R*C) in bf16, plus transposed copy
__global__ __launch_bounds__(256) void k_z0h(const float* __restrict__ a2,
                                             const unsigned* __restrict__ scal,
                                             unsigned short* __restrict__ zh,
                                             unsigned short* __restrict__ zTh) {
  int idx = blockIdx.x * 256 + threadIdx.x;
  float inv = 1.f / (__uint_as_float(scal[0]) * __uint_as_float(scal[1]));
  int bh = idx >> 16, r = (idx >> 8) & 255, c = idx & 255;
  zh[idx]  = f2b(a2[((size_t)bh << 16) + (c << 8) + r] * inv);
  zTh[idx] = f2b(a2[idx] * inv);
}

// batched pinv GEMM
__global__ __launch_bounds__(256) void k_pg_mfma(const unsigned short* __restrict__ A,
                                                 const unsigned short* __restrict__ Bsrc,
                                                 unsigned short* __restrict__ C,
                                                 unsigned short* __restrict__ CT,
                                                 float g, float bI, float s) {
  __shared__ short As[128 * 32], Bs[128 * 32];
  int tid = threadIdx.x, l = tid & 63, wid = tid >> 6;
  int wrow = (wid >> 1) * 64, wcol = (wid & 1) * 64;
  int bh = blockIdx.z;
  int i0 = blockIdx.y * 128, j0 = blockIdx.x * 128;
  A += (size_t)bh * 65536; Bsrc += (size_t)bh * 65536;
  f32x4 acc[4][4] = {};
  for (int k0 = 0; k0 < 256; k0 += 32) {
    __syncthreads();
    stage32<128>(A + (size_t)i0 * 256 + k0, 256, As, tid);
#pragma unroll
    for (int t = tid; t < 512; t += 256) {
      int r = t >> 2, c = t & 3;
      uint4 vv = *(const uint4*)(Bsrc + (size_t)(j0 + r) * 256 + k0 + c * 8);
      unsigned short* e = (unsigned short*)&vv;
      int n = j0 + r, kb = k0 + c * 8;
#pragma unroll
      for (int q = 0; q < 8; ++q) {
        float f = b2f(e[q]) * g + ((n == kb + q) ? bI : 0.f);
        e[q] = f2b(f);
      }
      *(uint4*)(Bs + r * 32 + c * 8) = vv;
    }
    __syncthreads();
    mma_step32(As, Bs, wrow, wcol, l, acc);
  }
#pragma unroll
  for (int i = 0; i < 4; ++i)
#pragma unroll
    for (int j = 0; j < 4; ++j) {
      int col = j0 + wcol + j * 16 + (l & 15);
      int row0 = i0 + wrow + i * 16 + (l >> 4) * 4;
      float v0 = acc[i][j][0] * s, v1 = acc[i][j][1] * s;
      float v2 = acc[i][j][2] * s, v3 = acc[i][j][3] * s;
      ushort4 hv; hv.x = f2b(v0); hv.y = f2b(v1); hv.z = f2b(v2); hv.w = f2b(v3);
      if (CT) *(ushort4*)&CT[(size_t)bh * 65536 + (size_t)col * 256 + row0] = hv;
      if (C) {
        unsigned short* cb = C + (size_t)bh * 65536 + (size_t)row0 * 256 + col;
        cb[0] = hv.x; cb[256] = hv.y; cb[512] = hv.z; cb[768] = hv.w;
      }
    }
}

// sim3 = q_land @ k^T -> bf16 [bh][256][4096]
__global__ __launch_bounds__(256) void k_sim3_mfma(const unsigned short* __restrict__ qlh,
                                                   const unsigned short* __restrict__ kh,
                                                   unsigned short* __restrict__ sim3h) {
  __shared__ short As[128 * 32], Bs[128 * 32];
  int tid = threadIdx.x, l = tid & 63, wid = tid >> 6;
  int wrow = (wid >> 1) * 64, wcol = (wid & 1) * 64;
  int bh = blockIdx.z;
  int m0 = blockIdx.y * 128, n0 = blockIdx.x * 128;
  const unsigned short* A = qlh + (size_t)bh * 256 * 64;
  const unsigned short* B = kh + (size_t)bh * 4096 * 64;
  f32x4 acc[4][4] = {};
  for (int k0 = 0; k0 < 64; k0 += 32) {
    __syncthreads();
    stage32<128>(A + (size_t)m0 * 64 + k0, 64, As, tid);
    stage32<128>(B + (size_t)n0 * 64 + k0, 64, Bs, tid);
    __syncthreads();
    mma_step32(As, Bs, wrow, wcol, l, acc);
  }
  unsigned short* Cm = sim3h + (size_t)bh * 1048576;
#pragma unroll
  for (int i = 0; i < 4; ++i)
#pragma unroll
    for (int j = 0; j < 4; ++j) {
      int col = n0 + wcol + j * 16 + (l & 15);
      int row0 = m0 + wrow + i * 16 + (l >> 4) * 4;
#pragma unroll
      for (int r = 0; r < 4; ++r)
        Cm[(size_t)(row0 + r) * 4096 + col] = f2b(acc[i][j][r]);
    }
}

// in-place row softmax over 4096 (bf16)
__global__ __launch_bounds__(256) void k_sm4096h(unsigned short* __restrict__ sim) {
  __shared__ float s4[4];
  int m = blockIdx.x, bh = blockIdx.y, tid = threadIdx.x;
  unsigned short* row = sim + ((size_t)bh * 256 + m) * 4096;
  float v[16];
  float mx = -1e30f;
#pragma unroll
  for (int i = 0; i < 16; ++i) { v[i] = b2f(row[i * 256 + tid]); mx = fmaxf(mx, v[i]); }
  mx = block_red(mx, s4, false);
  float ssum = 0;
#pragma unroll
  for (int i = 0; i < 16; ++i) { v[i] = expf(v[i] - mx); ssum += v[i]; }
  ssum = block_red(ssum, s4, true);
  float inv = 1.f / ssum;
#pragma unroll
  for (int i = 0; i < 16; ++i) row[i * 256 + tid] = f2b(v[i] * inv);
}

// a3 @ v split-K
__global__ __launch_bounds__(256) void k_a3v_mfma(const unsigned short* __restrict__ a3h,
                                                  const unsigned short* __restrict__ vTh,
                                                  float* __restrict__ part) {
  __shared__ short As[256 * 32], Bs[64 * 32];
  int tid = threadIdx.x, l = tid & 63, wid = tid >> 6;
  int wrow = wid * 64, wcol = 0;
  int kc = blockIdx.x, bh = blockIdx.z;
  const unsigned short* A = a3h + (size_t)bh * 1048576 + kc * 512;
  const unsigned short* B = vTh + (size_t)bh * 262144 + kc * 512;
  f32x4 acc[4][4] = {};
  for (int k0 = 0; k0 < 512; k0 += 32) {
    __syncthreads();
    stage32<256>(A + k0, 4096, As, tid);
    stage32<64>(B + k0, 4096, Bs, tid);
    __syncthreads();
    mma_step32(As, Bs, wrow, wcol, l, acc);
  }
  float* P = part + ((size_t)(kc * 16 + bh)) * 16384;
#pragma unroll
  for (int i = 0; i < 4; ++i)
#pragma unroll
    for (int j = 0; j < 4; ++j) {
      int col = j * 16 + (l & 15);
      int row0 = wrow + i * 16 + (l >> 4) * 4;
#pragma unroll
      for (int r = 0; r < 4; ++r)
        P[(size_t)(row0 + r) * 64 + col] = acc[i][j][r];
    }
}

// reduce split-K partials -> a3vT bf16 [bh][64][256]
__global__ __launch_bounds__(256) void k_a3v_redT(const float* __restrict__ part,
                                                  unsigned short* __restrict__ a3vT) {
  int idx = blockIdx.x * 256 + threadIdx.x;
  int m = idx & 255, d = (idx >> 8) & 63, bh = idx >> 14;
  float s = 0;
#pragma unroll
  for (int c = 0; c < 8; ++c) s += part[((size_t)(c * 16 + bh) * 256 + m) * 64 + d];
  a3vT[idx] = f2b(s);
}

// wm = z @ a3v -> wmT bf16 [bh][64 d][256 m]
__global__ __launch_bounds__(256) void k_wm_mfma(const unsigned short* __restrict__ zh,
                                                 const unsigned short* __restrict__ a3vTh,
                                                 unsigned short* __restrict__ wmTh) {
  __shared__ short As[256 * 32], Bs[64 * 32];
  int tid = threadIdx.x, l = tid & 63, wid = tid >> 6;
  int wrow = wid * 64, wcol = 0;
  int bh = blockIdx.z;
  const unsigned short* A = zh + (size_t)bh * 65536;
  const unsigned short* B = a3vTh + (size_t)bh * 16384;
  f32x4 acc[4][4] = {};
  for (int k0 = 0; k0 < 256; k0 += 32) {
    __syncthreads();
    stage32<256>(A + k0, 256, As, tid);
    stage32<64>(B + k0, 256, Bs, tid);
    __syncthreads();
    mma_step32(As, Bs, wrow, wcol, l, acc);
  }
  unsigned short* W = wmTh + (size_t)bh * 16384;
#pragma unroll
  for (int i = 0; i < 4; ++i)
#pragma unroll
    for (int j = 0; j < 4; ++j) {
      int col = j * 16 + (l & 15);                 // d
      int row0 = wrow + i * 16 + (l >> 4) * 4;     // m
#pragma unroll
      for (int r = 0; r < 4; ++r)
        W[(size_t)col * 256 + row0 + r] = f2b(acc[i][j][r]);
    }
}

// ---------------- fused attention tail, MFMA ----------------
// block = 128 tokens x 1 head, 512 threads (8 waves, 16 rows each)
// LDS union: ph1 {q[128][64]swz @0 (16K), kl[256][64]swz @16384 (32K)}
//            ph2 {wmT[64][256]swz @0 (32K), P[128][64]swz @32768 (16K)}
//            ph3 {out f32 [128][64] @0 (32K), v bf16 [160][68] @32768 (21760)}
#define FSM_Q    0
#define FSM_KL   16384
#define FSM_WMT  0
#define FSM_P    32768
#define FSM_OUT  0
#define FSM_V    32768
__global__ __launch_bounds__(512) void k_fused_mfma(const unsigned short* __restrict__ qh,
                                                    const unsigned short* __restrict__ klh,
                                                    const unsigned short* __restrict__ wmTh,
                                                    const float* __restrict__ vf,
                                                    const float* __restrict__ cw,
                                                    unsigned short* __restrict__ yh) {
  __shared__ char sm[54528];
  int tid = threadIdx.x, l = tid & 63, w = tid >> 6;
  int h = blockIdx.y, b = blockIdx.z, bh = b * HEADS + h;
  int n0 = blockIdx.x * 128;
  const char* qg = (const char*)(qh + ((size_t)bh * 4096 + n0) * 64);
  const char* kg = (const char*)(klh + (size_t)bh * 256 * 64);

  // stage q (swizzled) and kl (swizzled)
#pragma unroll
  for (int u = tid; u < 1024; u += 512) {
    int row = u >> 3, cb = (u & 7) * 16;
    *(uint4*)(sm + FSM_Q + row * 128 + (cb ^ ((row & 7) << 4))) =
        *(const uint4*)(qg + row * 128 + cb);
  }
#pragma unroll
  for (int u = tid; u < 2048; u += 512) {
    int row = u >> 3, cb = (u & 7) * 16;
    *(uint4*)(sm + FSM_KL + row * 128 + (cb ^ ((row & 7) << 4))) =
        *(const uint4*)(kg + row * 128 + cb);
  }
  __syncthreads();

  int lr = l & 15, lkb = (l >> 4) * 16;
  int arow = 16 * w + lr;
  int aswz = (arow & 7) << 4;
  f32x4 acc[16] = {};
#pragma unroll
  for (int ks = 0; ks < 2; ++ks) {
    bf16x8 af = *(const bf16x8*)(sm + FSM_Q + arow * 128 + ((ks * 64 + lkb) ^ aswz));
#pragma unroll
    for (int j = 0; j < 16; ++j) {
      int brow = j * 16 + lr;
      bf16x8 bf_ = *(const bf16x8*)(sm + FSM_KL + brow * 128 + ((ks * 64 + lkb) ^ ((brow & 7) << 4)));
      acc[j] = __builtin_amdgcn_mfma_f32_16x16x32_bf16(af, bf_, acc[j], 0, 0, 0);
    }
  }

  // in-register row softmax (row on 16 lanes x 16 j-frags)
#pragma unroll
  for (int r = 0; r < 4; ++r) {
    float mx = -1e30f;
#pragma unroll
    for (int j = 0; j < 16; ++j) mx = fmaxf(mx, acc[j][r]);
#pragma unroll
    for (int o = 8; o; o >>= 1) mx = fmaxf(mx, __shfl_xor(mx, o));
    float s = 0.f;
#pragma unroll
    for (int j = 0; j < 16; ++j) { float e = expf(acc[j][r] - mx); acc[j][r] = e; s += e; }
#pragma unroll
    for (int o = 8; o; o >>= 1) s += __shfl_xor(s, o);
    float inv = 1.f / s;
#pragma unroll
    for (int j = 0; j < 16; ++j) acc[j][r] *= inv;
  }
  __syncthreads();

  // stage wmT (swizzled)
  const char* wg = (const char*)(wmTh + (size_t)bh * 16384);
#pragma unroll
  for (int u = tid; u < 2048; u += 512) {
    int row = u >> 5, cb = (u & 31) * 16;
    *(uint4*)(sm + FSM_WMT + row * 512 + (cb ^ ((row & 7) << 4))) =
        *(const uint4*)(wg + row * 512 + cb);
  }

  f32x4 acc2[4] = {};
  int prow0 = 16 * w + (l >> 4) * 4;
#pragma unroll
  for (int mc = 0; mc < 4; ++mc) {
    __syncthreads();
#pragma unroll
    for (int j2 = 0; j2 < 4; ++j2)
#pragma unroll
      for (int r = 0; r < 4; ++r) {
        int row = prow0 + r;
        int colb = (j2 * 16 + lr) * 2;
        *(unsigned short*)(sm + FSM_P + row * 128 + (colb ^ ((row & 7) << 4))) =
            f2b(acc[mc * 4 + j2][r]);
      }
    __syncthreads();
#pragma unroll
    for (int ks = 0; ks < 2; ++ks) {
      bf16x8 af = *(const bf16x8*)(sm + FSM_P + arow * 128 + ((ks * 64 + lkb) ^ aswz));
#pragma unroll
      for (int j = 0; j < 4; ++j) {
        int brow = j * 16 + lr;
        bf16x8 bf_ = *(const bf16x8*)(sm + FSM_WMT + brow * 512 +
                                      ((mc * 128 + ks * 64 + lkb) ^ ((brow & 7) << 4)));
        acc2[j] = __builtin_amdgcn_mfma_f32_16x16x32_bf16(af, bf_, acc2[j], 0, 0, 0);
      }
    }
  }
  __syncthreads();

  // park PV result in LDS f32
#pragma unroll
  for (int j = 0; j < 4; ++j)
#pragma unroll
    for (int r = 0; r < 4; ++r)
      *(float*)(sm + FSM_OUT + (prow0 + r) * 256 + (j * 16 + lr) * 4) = acc2[j][r];

  // stage v halo bf16 [160][68]
  const float* vg = vf + (size_t)bh * 4096 * 64;
#pragma unroll
  for (int u = tid; u < 2560; u += 512) {
    int row = u >> 4, c4 = (u & 15) * 4;
    int n = n0 - 16 + row;
    float4 vv = make_float4(0.f, 0.f, 0.f, 0.f);
    if (n >= 0 && n < 4096) vv = *(const float4*)(vg + (size_t)n * 64 + c4);
    ushort4 hv; hv.x = f2b(vv.x); hv.y = f2b(vv.y); hv.z = f2b(vv.z); hv.w = f2b(vv.w);
    *(ushort4*)(sm + FSM_V + row * 136 + c4 * 2) = hv;
  }
  __syncthreads();

  // conv + add + store
#pragma unroll
  for (int u = tid; u < 1024; u += 512) {
    int row = u >> 3, d8 = (u & 7) * 8;
    float r8[8] = {};
#pragma unroll 1
    for (int t = 0; t < KCONV; ++t) {
      float wt = cw[h * KCONV + t];  // uniform -> scalar load
      ushort4 a0 = *(const ushort4*)(sm + FSM_V + (row + t) * 136 + d8 * 2);
      ushort4 a1 = *(const ushort4*)(sm + FSM_V + (row + t) * 136 + d8 * 2 + 8);
      r8[0] += wt * b2f(a0.x); r8[1] += wt * b2f(a0.y);
      r8[2] += wt * b2f(a0.z); r8[3] += wt * b2f(a0.w);
      r8[4] += wt * b2f(a1.x); r8[5] += wt * b2f(a1.y);
      r8[6] += wt * b2f(a1.z); r8[7] += wt * b2f(a1.w);
    }
    const float* ol = (const float*)(sm + FSM_OUT + row * 256 + d8 * 4);
    ushort4 s0, s1;
    s0.x = f2b(r8[0] + ol[0]); s0.y = f2b(r8[1] + ol[1]);
    s0.z = f2b(r8[2] + ol[2]); s0.w = f2b(r8[3] + ol[3]);
    s1.x = f2b(r8[4] + ol[4]); s1.y = f2b(r8[5] + ol[5]);
    s1.z = f2b(r8[6] + ol[6]); s1.w = f2b(r8[7] + ol[7]);
    unsigned short* yp = yh + ((size_t)b * 4096 + n0 + row) * 512 + h * 64 + d8;
    *(ushort4*)yp = s0;
    *(ushort4*)(yp + 4) = s1;
  }
}

// out = x + y @ out_w^T + out_b  (MFMA)
__global__ __launch_bounds__(256) void k_outproj_mfma(const unsigned short* __restrict__ yh,
                                                      const unsigned short* __restrict__ owh,
                                                      const float* __restrict__ bias,
                                                      const float* __restrict__ x,
                                                      float* __restrict__ out) {
  __shared__ short As[128 * 32], Bs[128 * 32];
  int tid = threadIdx.x, l = tid & 63, wid = tid >> 6;
  int wrow = (wid >> 1) * 64, wcol = (wid & 1) * 64;
  int m0 = blockIdx.y * 128, c0 = blockIdx.x * 128;
  f32x4 acc[4][4] = {};
  for (int k0 = 0; k0 < 512; k0 += 32) {
    __syncthreads();
    stage32<128>(yh + (size_t)m0 * 512 + k0, 512, As, tid);
    stage32<128>(owh + (size_t)c0 * 512 + k0, 512, Bs, tid);
    __syncthreads();
    mma_step32(As, Bs, wrow, wcol, l, acc);
  }
#pragma unroll
  for (int i = 0; i < 4; ++i)
#pragma unroll
    for (int j = 0; j < 4; ++j) {
      int col = c0 + wcol + j * 16 + (l & 15);
      int row0 = m0 + wrow + i * 16 + (l >> 4) * 4;
      float bb = bias[col];
#pragma unroll
      for (int r = 0; r < 4; ++r) {
        size_t o = (size_t)(row0 + r) * 512 + col;
        out[o] = acc[i][j][r] + x[o] + bb;
      }
    }
}

// ---------------- launcher ----------------
extern "C" void kernel_launch(void* const* d_in, const int* in_sizes, int n_in,
                              void* d_out, int out_size, void* d_ws, size_t ws_size,
                              hipStream_t stream) {
  const float* x      = (const float*)d_in[0];
  const float* ln_w   = (const float*)d_in[1];
  const float* ln_b   = (const float*)d_in[2];
  const float* qkv_w  = (const float*)d_in[3];
  const float* out_w  = (const float*)d_in[4];
  const float* out_b  = (const float*)d_in[5];
  const float* conv_w = (const float*)d_in[6];
  float* out = (float*)d_out;

  float* qf   = (float*)WB(d_ws, 0);
  float* kf   = (float*)WB(d_ws, 16);
  float* vf   = (float*)WB(d_ws, 32);
  float* ql   = (float*)WB(d_ws, 48);
  float* kl   = (float*)WB(d_ws, 49);
  float* a2   = (float*)WB(d_ws, 50);
  float* part = (float*)WB(d_ws, 54);
  unsigned* scal = (unsigned*)WB(d_ws, 63);
  unsigned short* xnh  = (unsigned short*)WB(d_ws, 64);
  unsigned short* wqh  = (unsigned short*)WB(d_ws, 72);
  unsigned short* owh  = (unsigned short*)WB(d_ws, 74);
  unsigned short* kh   = (unsigned short*)WB(d_ws, 76);
  unsigned short* vTh  = (unsigned short*)WB(d_ws, 84);
  unsigned short* qlh  = (unsigned short*)WB(d_ws, 92);
  unsigned short* a2h  = (unsigned short*)WB(d_ws, 93);
  unsigned short* zA   = (unsigned short*)WB(d_ws, 95);
  unsigned short* zAT  = (unsigned short*)WB(d_ws, 97);
  unsigned short* zB   = (unsigned short*)WB(d_ws, 99);
  unsigned short* zBT  = (unsigned short*)WB(d_ws, 101);
  unsigned short* Am   = (unsigned short*)WB(d_ws, 103);
  unsigned short* AmT  = (unsigned short*)WB(d_ws, 105);
  unsigned short* W2T  = (unsigned short*)WB(d_ws, 107);
  unsigned short* W4T  = (unsigned short*)WB(d_ws, 109);
  unsigned short* sim3h= (unsigned short*)WB(d_ws, 111);
  unsigned short* a3vTh= (unsigned short*)WB(d_ws, 143);
  unsigned short* yh   = (unsigned short*)WB(d_ws, 144);
  unsigned short* qhb  = (unsigned short*)WB(d_ws, 152);
  unsigned short* klhb = (unsigned short*)WB(d_ws, 168);
  unsigned short* wmTh = (unsigned short*)WB(d_ws, 169);

  k_init<<<1, 64, 0, stream>>>(scal);
  k_ln<<<2048, 256, 0, stream>>>(x, ln_w, ln_b, xnh);
  k_wconv<<<4096, 256, 0, stream>>>(qkv_w, out_w, wqh, owh);
  k_qkv_mfma<<<dim3(12, 64), 256, 0, stream>>>(xnh, wqh, qf, kf, vf, qhb, kh, vTh);
  k_land<<<2048, 256, 0, stream>>>(qf, kf, ql, kl, qlh, klhb);
  k_sim2<<<dim3(256, 16), 256, 0, stream>>>(ql, kl, a2, a2h);
  k_pinv_red<<<16, 256, 0, stream>>>(a2, scal);
  k_z0h<<<4096, 256, 0, stream>>>(a2, scal, zA, zAT);

  unsigned short *zc = zA, *zcT = zAT, *zn = zB, *znT = zBT;
  dim3 gpg(2, 2, 16);
  for (int it = 0; it < 6; ++it) {
    k_pg_mfma<<<gpg, 256, 0, stream>>>(a2h, zcT, Am, AmT, 1.f, 0.f, 1.f);
    k_pg_mfma<<<gpg, 256, 0, stream>>>(Am, AmT, (unsigned short*)nullptr, W2T, -1.f, 7.f, 1.f);
    k_pg_mfma<<<gpg, 256, 0, stream>>>(Am, W2T, (unsigned short*)nullptr, W4T, -1.f, 15.f, 1.f);
    k_pg_mfma<<<gpg, 256, 0, stream>>>(zc, W4T, zn, znT, -1.f, 13.f, 0.25f);
    unsigned short* t;
    t = zc; zc = zn; zn = t;
    t = zcT; zcT = znT; znT = t;
  }

  k_sim3_mfma<<<dim3(32, 2, 16), 256, 0, stream>>>(qlh, kh, sim3h);
  k_sm4096h<<<dim3(256, 16), 256, 0, stream>>>(sim3h);
  k_a3v_mfma<<<dim3(8, 1, 16), 256, 0, stream>>>(sim3h, vTh, part);
  k_a3v_redT<<<1024, 256, 0, stream>>>(part, a3vTh);
  k_wm_mfma<<<dim3(1, 1, 16), 256, 0, stream>>>(zc, a3vTh, wmTh);
  k_fused_mfma<<<dim3(32, 8, 2), 512, 0, stream>>>(qhb, klhb, wmTh, vf, conv_w, yh);
  k_outproj_mfma<<<dim3(4, 64), 256, 0, stream>>>(yh, owh, out_b, x, out);
}